// Round 1
// baseline (427.301 us; speedup 1.0000x reference)
//
#include <hip/hip_runtime.h>
#include <math.h>

// GAT layer: N=50000 nodes, E=800000 edges, D_IN=D_OUT=128, H=4, D_H=32
//
// Pipeline:
//   k_gemm1 : Wx = x @ W  (+ fused per-node attention scores s_i, s_j)
//   k_hist  : in-degree histogram by dst
//   k_scan  : exclusive prefix sum -> CSR offsets (single block)
//   k_fill  : scatter edge src indices into CSR slots
//   k_agg   : per-node (1 wave/node) softmax over in-edges + pull aggregation
//             writes agg directly into d_out
//   k_gemm2 : in-place row transform d_out = elu(d_out @ out_w + out_b)

__device__ __forceinline__ float lrelu(float v) { return v >= 0.f ? v : 0.2f * v; }

// ---------------------------------------------------------------- GEMM 1
// One wave computes 8 rows of Wx (each lane owns 2 columns), then the
// per-row attention scores s_i[n][h], s_j[n][h] via 16-lane reductions.
__global__ void k_gemm1(const float* __restrict__ x, const float* __restrict__ W,
                        const float* __restrict__ attn, float* __restrict__ Wx,
                        float* __restrict__ s_i, float* __restrict__ s_j, int n) {
  const int lane = threadIdx.x & 63;
  const int gw = blockIdx.x * (blockDim.x >> 6) + (threadIdx.x >> 6);
  const int r0 = gw * 8;
  if (r0 >= n) return;
  const float2* W2 = (const float2*)W;
  float2 acc[8];
#pragma unroll
  for (int r = 0; r < 8; ++r) acc[r] = make_float2(0.f, 0.f);
  const float* xb = x + (size_t)r0 * 128;
  for (int k = 0; k < 128; k += 4) {
    float2 w0 = W2[(k + 0) * 64 + lane];
    float2 w1 = W2[(k + 1) * 64 + lane];
    float2 w2 = W2[(k + 2) * 64 + lane];
    float2 w3 = W2[(k + 3) * 64 + lane];
#pragma unroll
    for (int r = 0; r < 8; ++r) {
      float4 xv = *(const float4*)(xb + r * 128 + k);  // wave-uniform broadcast
      acc[r].x += xv.x * w0.x; acc[r].y += xv.x * w0.y;
      acc[r].x += xv.y * w1.x; acc[r].y += xv.y * w1.y;
      acc[r].x += xv.z * w2.x; acc[r].y += xv.z * w2.y;
      acc[r].x += xv.w * w3.x; acc[r].y += xv.w * w3.y;
    }
  }
  const int h = lane >> 4;         // head of this lane's 2 columns
  const int d = (lane & 15) * 2;   // offset within head
  const float2 ai = *(const float2*)(attn + h * 64 + d);       // a_i[h][d..d+1]
  const float2 aj = *(const float2*)(attn + h * 64 + 32 + d);  // a_j[h][d..d+1]
#pragma unroll
  for (int r = 0; r < 8; ++r) {
    ((float2*)(Wx + (size_t)(r0 + r) * 128))[lane] = acc[r];
    float pi = acc[r].x * ai.x + acc[r].y * ai.y;
    float pj = acc[r].x * aj.x + acc[r].y * aj.y;
#pragma unroll
    for (int m = 1; m < 16; m <<= 1) {
      pi += __shfl_xor(pi, m, 64);
      pj += __shfl_xor(pj, m, 64);
    }
    if ((lane & 15) == 0) {
      s_i[(size_t)(r0 + r) * 4 + h] = pi;
      s_j[(size_t)(r0 + r) * 4 + h] = pj;
    }
  }
}

// ---------------------------------------------------------------- histogram
__global__ void k_hist(const int* __restrict__ dst, int* __restrict__ cnts, int E) {
  int e = blockIdx.x * 256 + threadIdx.x;
  if (e < E) atomicAdd(&cnts[dst[e]], 1);
}

// ---------------------------------------------------------------- scan
// Single-block exclusive prefix sum of cnts -> offs (and a copy into cursor).
__global__ void k_scan(const int* __restrict__ cnts, int* __restrict__ offs,
                       int* __restrict__ cursor, int n) {
  __shared__ int wsum[16];
  __shared__ int carry_s;
  const int lane = threadIdx.x & 63;
  const int wv = threadIdx.x >> 6;
  if (threadIdx.x == 0) carry_s = 0;
  __syncthreads();
  for (int base = 0; base < n; base += 1024) {
    const int i = base + (int)threadIdx.x;
    int v = (i < n) ? cnts[i] : 0;
    int incl = v;
#pragma unroll
    for (int off = 1; off < 64; off <<= 1) {
      int t = __shfl_up(incl, off, 64);
      if (lane >= off) incl += t;
    }
    if (lane == 63) wsum[wv] = incl;
    __syncthreads();
    int carry = carry_s;
    int woff = 0;
    for (int p = 0; p < wv; ++p) woff += wsum[p];
    int excl = carry + woff + incl - v;
    if (i < n) { offs[i] = excl; cursor[i] = excl; }
    __syncthreads();
    if (threadIdx.x == 0) {
      int tot = 0;
      for (int p = 0; p < 16; ++p) tot += wsum[p];
      carry_s = carry + tot;
    }
    __syncthreads();
  }
}

// ---------------------------------------------------------------- CSR fill
__global__ void k_fill(const int* __restrict__ edges, int* __restrict__ cursor,
                       int* __restrict__ csr_src, int E) {
  int e = blockIdx.x * 256 + threadIdx.x;
  if (e < E) {
    int d = edges[E + e];
    int pos = atomicAdd(&cursor[d], 1);
    csr_src[pos] = edges[e];
  }
}

// ---------------------------------------------------------------- aggregate
// One wave per destination node: segment softmax over its in-edges, then
// pull-style weighted sum of Wx[src] rows. Lane l owns output cols 2l,2l+1
// (head h = l>>4).
__global__ void k_agg(const float* __restrict__ Wx, const float* __restrict__ s_i,
                      const float* __restrict__ s_j, const int* __restrict__ offs,
                      const int* __restrict__ cnts, const int* __restrict__ csr_src,
                      float* __restrict__ agg, int n) {
  const int lane = threadIdx.x & 63;
  const int nd = blockIdx.x * (blockDim.x >> 6) + (threadIdx.x >> 6);
  if (nd >= n) return;
  const int base = offs[nd];
  const int deg = cnts[nd];
  const float4 sj = *(const float4*)(s_j + (size_t)nd * 4);

  // pass 1: per-head max over in-edges (lane-parallel, then wave reduce)
  float4 mx = make_float4(-INFINITY, -INFINITY, -INFINITY, -INFINITY);
  for (int c = lane; c < deg; c += 64) {
    int src = csr_src[base + c];
    float4 si = *(const float4*)(s_i + (size_t)src * 4);
    mx.x = fmaxf(mx.x, lrelu(si.x + sj.x));
    mx.y = fmaxf(mx.y, lrelu(si.y + sj.y));
    mx.z = fmaxf(mx.z, lrelu(si.z + sj.z));
    mx.w = fmaxf(mx.w, lrelu(si.w + sj.w));
  }
#pragma unroll
  for (int m = 1; m < 64; m <<= 1) {
    mx.x = fmaxf(mx.x, __shfl_xor(mx.x, m, 64));
    mx.y = fmaxf(mx.y, __shfl_xor(mx.y, m, 64));
    mx.z = fmaxf(mx.z, __shfl_xor(mx.z, m, 64));
    mx.w = fmaxf(mx.w, __shfl_xor(mx.w, m, 64));
  }

  // pass 2: per-head sum of exp(e - max)
  float4 sm = make_float4(0.f, 0.f, 0.f, 0.f);
  for (int c = lane; c < deg; c += 64) {
    int src = csr_src[base + c];
    float4 si = *(const float4*)(s_i + (size_t)src * 4);
    sm.x += __expf(lrelu(si.x + sj.x) - mx.x);
    sm.y += __expf(lrelu(si.y + sj.y) - mx.y);
    sm.z += __expf(lrelu(si.z + sj.z) - mx.z);
    sm.w += __expf(lrelu(si.w + sj.w) - mx.w);
  }
#pragma unroll
  for (int m = 1; m < 64; m <<= 1) {
    sm.x += __shfl_xor(sm.x, m, 64);
    sm.y += __shfl_xor(sm.y, m, 64);
    sm.z += __shfl_xor(sm.z, m, 64);
    sm.w += __shfl_xor(sm.w, m, 64);
  }

  const int h = lane >> 4;
  float mh  = (h & 2) ? ((h & 1) ? mx.w : mx.z) : ((h & 1) ? mx.y : mx.x);
  float sh  = (h & 2) ? ((h & 1) ? sm.w : sm.z) : ((h & 1) ? sm.y : sm.x);
  float sjh = (h & 2) ? ((h & 1) ? sj.w : sj.z) : ((h & 1) ? sj.y : sj.x);
  const float inv = 1.f / (sh + 1e-16f);

  // pass 3: weighted aggregation (sequential over edges, wave-wide row loads)
  float2 a2 = make_float2(0.f, 0.f);
  const float2* Wx2 = (const float2*)Wx;
  for (int k = 0; k < deg; ++k) {
    int src = csr_src[base + k];                 // wave-uniform broadcast
    float e = lrelu(s_i[(size_t)src * 4 + h] + sjh);
    float al = __expf(e - mh) * inv;
    float2 wv = Wx2[(size_t)src * 64 + lane];    // coalesced 512B row load
    a2.x += al * wv.x;
    a2.y += al * wv.y;
  }
  ((float2*)agg)[(size_t)nd * 64 + lane] = a2;
}

// ---------------------------------------------------------------- GEMM 2
// In-place row transform: io = elu(io @ out_w + out_b). Safe in place since
// each wave reads its 8 rows fully before writing them.
__global__ void k_gemm2(float* __restrict__ io, const float* __restrict__ ow,
                        const float* __restrict__ ob, int n) {
  const int lane = threadIdx.x & 63;
  const int gw = blockIdx.x * (blockDim.x >> 6) + (threadIdx.x >> 6);
  const int r0 = gw * 8;
  if (r0 >= n) return;
  const float2* W2 = (const float2*)ow;
  float2 acc[8];
#pragma unroll
  for (int r = 0; r < 8; ++r) acc[r] = make_float2(0.f, 0.f);
  const float* xb = io + (size_t)r0 * 128;
  for (int k = 0; k < 128; k += 4) {
    float2 w0 = W2[(k + 0) * 64 + lane];
    float2 w1 = W2[(k + 1) * 64 + lane];
    float2 w2 = W2[(k + 2) * 64 + lane];
    float2 w3 = W2[(k + 3) * 64 + lane];
#pragma unroll
    for (int r = 0; r < 8; ++r) {
      float4 xv = *(const float4*)(xb + r * 128 + k);
      acc[r].x += xv.x * w0.x; acc[r].y += xv.x * w0.y;
      acc[r].x += xv.y * w1.x; acc[r].y += xv.y * w1.y;
      acc[r].x += xv.z * w2.x; acc[r].y += xv.z * w2.y;
      acc[r].x += xv.w * w3.x; acc[r].y += xv.w * w3.y;
    }
  }
  const float2 b2 = ((const float2*)ob)[lane];
#pragma unroll
  for (int r = 0; r < 8; ++r) {
    float ox = acc[r].x + b2.x;
    float oy = acc[r].y + b2.y;
    ox = ox > 0.f ? ox : expm1f(ox);
    oy = oy > 0.f ? oy : expm1f(oy);
    ((float2*)io)[(size_t)(r0 + r) * 64 + lane] = make_float2(ox, oy);
  }
}

// ---------------------------------------------------------------- launch
extern "C" void kernel_launch(void* const* d_in, const int* in_sizes, int n_in,
                              void* d_out, int out_size, void* d_ws, size_t ws_size,
                              hipStream_t stream) {
  const float* x    = (const float*)d_in[0];
  const int*   edges = (const int*)d_in[1];   // [2,E] int (src row then dst row)
  const float* W    = (const float*)d_in[2];
  const float* attn = (const float*)d_in[3];
  const float* ow   = (const float*)d_in[4];
  const float* ob   = (const float*)d_in[5];
  const int n = in_sizes[0] / 128;
  const int E = in_sizes[1] / 2;
  float* out = (float*)d_out;

  char* wp = (char*)d_ws;
  auto alloc = [&](size_t bytes) {
    char* p = wp;
    wp += (bytes + 255) & ~(size_t)255;
    return p;
  };
  float* Wx     = (float*)alloc((size_t)n * 128 * 4);
  float* s_i    = (float*)alloc((size_t)n * 4 * 4);
  float* s_j    = (float*)alloc((size_t)n * 4 * 4);
  int*   cnts   = (int*)alloc((size_t)n * 4);
  int*   offs   = (int*)alloc((size_t)n * 4);
  int*   cursor = (int*)alloc((size_t)n * 4);
  int*   csr    = (int*)alloc((size_t)E * 4);

  hipMemsetAsync(cnts, 0, (size_t)n * 4, stream);

  dim3 blk(256);
  const int gw1 = (n + 7) / 8;  // waves for the two GEMMs (8 rows/wave)
  k_gemm1<<<(gw1 + 3) / 4, blk, 0, stream>>>(x, W, attn, Wx, s_i, s_j, n);
  k_hist<<<(E + 255) / 256, blk, 0, stream>>>(edges + E, cnts, E);
  k_scan<<<1, 1024, 0, stream>>>(cnts, offs, cursor, n);
  k_fill<<<(E + 255) / 256, blk, 0, stream>>>(edges, cursor, csr, E);
  k_agg<<<(n + 3) / 4, blk, 0, stream>>>(Wx, s_i, s_j, offs, cnts, csr, out, n);
  k_gemm2<<<(gw1 + 3) / 4, blk, 0, stream>>>(out, ow, ob, n);
}

// Round 2
// 344.439 us; speedup vs baseline: 1.2406x; 1.2406x over previous
//
#include <hip/hip_runtime.h>
#include <math.h>

// GAT layer: N=50000 nodes, E=800000 edges, D_IN=D_OUT=128, H=4, D_H=32
//
// Pipeline:
//   k_gemm1 : Wx = x @ W  (+ fused per-node attention scores s_i, s_j)
//   k_hist  : in-degree histogram by dst
//   k_scan1/2/3 : 3-phase exclusive prefix sum -> CSR offsets (multi-block)
//   k_fill  : scatter edge src indices into CSR slots
//   k_agg   : per-node (1 wave/node) softmax + pull aggregation, LDS-staged
//             per-edge state, 4-way ILP on the Wx row gather
//   k_gemm2 : in-place row transform d_out = elu(d_out @ out_w + out_b)

__device__ __forceinline__ float lrelu(float v) { return v >= 0.f ? v : 0.2f * v; }

// ---------------------------------------------------------------- GEMM 1
__global__ void k_gemm1(const float* __restrict__ x, const float* __restrict__ W,
                        const float* __restrict__ attn, float* __restrict__ Wx,
                        float* __restrict__ s_i, float* __restrict__ s_j, int n) {
  const int lane = threadIdx.x & 63;
  const int gw = blockIdx.x * (blockDim.x >> 6) + (threadIdx.x >> 6);
  const int r0 = gw * 8;
  if (r0 >= n) return;
  const float2* W2 = (const float2*)W;
  float2 acc[8];
#pragma unroll
  for (int r = 0; r < 8; ++r) acc[r] = make_float2(0.f, 0.f);
  const float* xb = x + (size_t)r0 * 128;
  for (int k = 0; k < 128; k += 4) {
    float2 w0 = W2[(k + 0) * 64 + lane];
    float2 w1 = W2[(k + 1) * 64 + lane];
    float2 w2 = W2[(k + 2) * 64 + lane];
    float2 w3 = W2[(k + 3) * 64 + lane];
#pragma unroll
    for (int r = 0; r < 8; ++r) {
      float4 xv = *(const float4*)(xb + r * 128 + k);  // wave-uniform broadcast
      acc[r].x += xv.x * w0.x; acc[r].y += xv.x * w0.y;
      acc[r].x += xv.y * w1.x; acc[r].y += xv.y * w1.y;
      acc[r].x += xv.z * w2.x; acc[r].y += xv.z * w2.y;
      acc[r].x += xv.w * w3.x; acc[r].y += xv.w * w3.y;
    }
  }
  const int h = lane >> 4;
  const int d = (lane & 15) * 2;
  const float2 ai = *(const float2*)(attn + h * 64 + d);
  const float2 aj = *(const float2*)(attn + h * 64 + 32 + d);
#pragma unroll
  for (int r = 0; r < 8; ++r) {
    ((float2*)(Wx + (size_t)(r0 + r) * 128))[lane] = acc[r];
    float pi = acc[r].x * ai.x + acc[r].y * ai.y;
    float pj = acc[r].x * aj.x + acc[r].y * aj.y;
#pragma unroll
    for (int m = 1; m < 16; m <<= 1) {
      pi += __shfl_xor(pi, m, 64);
      pj += __shfl_xor(pj, m, 64);
    }
    if ((lane & 15) == 0) {
      s_i[(size_t)(r0 + r) * 4 + h] = pi;
      s_j[(size_t)(r0 + r) * 4 + h] = pj;
    }
  }
}

// ---------------------------------------------------------------- histogram
__global__ void k_hist(const int* __restrict__ dst, int* __restrict__ cnts, int E) {
  int e = blockIdx.x * 256 + threadIdx.x;
  if (e < E) atomicAdd(&cnts[dst[e]], 1);
}

// ---------------------------------------------------------------- scan (3 phases)
// phase 1: block b sums cnts[b*1024 .. b*1024+1024) -> part[b]
__global__ void k_scan1(const int* __restrict__ cnts, int* __restrict__ part, int n) {
  __shared__ int ws[4];
  const int t = threadIdx.x, lane = t & 63, wv = t >> 6;
  const int base = blockIdx.x * 1024 + t * 4;
  int s = 0;
  if (base + 3 < n) {
    int4 v = *(const int4*)(cnts + base);
    s = v.x + v.y + v.z + v.w;
  } else {
#pragma unroll
    for (int i = 0; i < 4; ++i) if (base + i < n) s += cnts[base + i];
  }
#pragma unroll
  for (int m = 1; m < 64; m <<= 1) s += __shfl_xor(s, m, 64);
  if (lane == 0) ws[wv] = s;
  __syncthreads();
  if (t == 0) part[blockIdx.x] = ws[0] + ws[1] + ws[2] + ws[3];
}

// phase 2: single wave exclusive-scans part[0..nb)
__global__ void k_scan2(int* __restrict__ part, int nb) {
  const int lane = threadIdx.x;
  int carry = 0;
  for (int b = 0; b < nb; b += 64) {
    const int i = b + lane;
    int v = (i < nb) ? part[i] : 0;
    int incl = v;
#pragma unroll
    for (int m = 1; m < 64; m <<= 1) {
      int t = __shfl_up(incl, m, 64);
      if (lane >= m) incl += t;
    }
    if (i < nb) part[i] = carry + incl - v;
    carry += __shfl(incl, 63, 64);
  }
}

// phase 3: block-local exclusive scan + block offset -> offs, cursor
__global__ void k_scan3(const int* __restrict__ cnts, const int* __restrict__ part,
                        int* __restrict__ offs, int* __restrict__ cursor, int n) {
  __shared__ int ws[4];
  const int t = threadIdx.x, lane = t & 63, wv = t >> 6;
  const int base = blockIdx.x * 1024 + t * 4;
  int4 v = make_int4(0, 0, 0, 0);
  if (base + 3 < n) {
    v = *(const int4*)(cnts + base);
  } else {
    if (base + 0 < n) v.x = cnts[base + 0];
    if (base + 1 < n) v.y = cnts[base + 1];
    if (base + 2 < n) v.z = cnts[base + 2];
    if (base + 3 < n) v.w = cnts[base + 3];
  }
  const int s = v.x + v.y + v.z + v.w;
  int incl = s;
#pragma unroll
  for (int m = 1; m < 64; m <<= 1) {
    int tt = __shfl_up(incl, m, 64);
    if (lane >= m) incl += tt;
  }
  if (lane == 63) ws[wv] = incl;
  __syncthreads();
  int woff = 0;
  for (int p = 0; p < wv; ++p) woff += ws[p];
  const int excl = part[blockIdx.x] + woff + incl - s;
  int4 o;
  o.x = excl; o.y = o.x + v.x; o.z = o.y + v.y; o.w = o.z + v.z;
  if (base + 3 < n) {
    *(int4*)(offs + base) = o;
    *(int4*)(cursor + base) = o;
  } else {
    if (base + 0 < n) { offs[base + 0] = o.x; cursor[base + 0] = o.x; }
    if (base + 1 < n) { offs[base + 1] = o.y; cursor[base + 1] = o.y; }
    if (base + 2 < n) { offs[base + 2] = o.z; cursor[base + 2] = o.z; }
    if (base + 3 < n) { offs[base + 3] = o.w; cursor[base + 3] = o.w; }
  }
}

// ---------------------------------------------------------------- CSR fill
__global__ void k_fill(const int* __restrict__ edges, int* __restrict__ cursor,
                       int* __restrict__ csr_src, int E) {
  int e = blockIdx.x * 256 + threadIdx.x;
  if (e < E) {
    int d = edges[E + e];
    int pos = atomicAdd(&cursor[d], 1);
    csr_src[pos] = edges[e];
  }
}

// ---------------------------------------------------------------- aggregate
// One wave per destination node. Per 64-edge chunk: lane-parallel gather of
// {src, exp4} staged to LDS, then a 4-way-unrolled serial loop where the only
// global loads are the (independent) Wx row gathers. Normalization (1/sum)
// is deferred to the final write, so exp-sum and aggregation fuse into one
// pass over the edges.
#define AGG_WPB 4
__global__ void k_agg(const float* __restrict__ Wx, const float* __restrict__ s_i,
                      const float* __restrict__ s_j, const int* __restrict__ offs,
                      const int* __restrict__ cnts, const int* __restrict__ csr_src,
                      float* __restrict__ agg, int n) {
  __shared__ int   lsrc[AGG_WPB][64];
  __shared__ float lp[AGG_WPB][64][4];
  const int lane = threadIdx.x & 63;
  const int wv = threadIdx.x >> 6;
  const int nd = blockIdx.x * AGG_WPB + wv;
  if (nd >= n) return;
  const int base = offs[nd];
  const int deg = cnts[nd];
  const float4 sj = *(const float4*)(s_j + (size_t)nd * 4);
  const int h = lane >> 4;

  // ---- pass A: per-head max over in-edges (lane-parallel + wave reduce)
  float4 mx = make_float4(-INFINITY, -INFINITY, -INFINITY, -INFINITY);
  for (int c = lane; c < deg; c += 64) {
    int src = csr_src[base + c];
    float4 si = *(const float4*)(s_i + (size_t)src * 4);
    mx.x = fmaxf(mx.x, lrelu(si.x + sj.x));
    mx.y = fmaxf(mx.y, lrelu(si.y + sj.y));
    mx.z = fmaxf(mx.z, lrelu(si.z + sj.z));
    mx.w = fmaxf(mx.w, lrelu(si.w + sj.w));
  }
#pragma unroll
  for (int m = 1; m < 64; m <<= 1) {
    mx.x = fmaxf(mx.x, __shfl_xor(mx.x, m, 64));
    mx.y = fmaxf(mx.y, __shfl_xor(mx.y, m, 64));
    mx.z = fmaxf(mx.z, __shfl_xor(mx.z, m, 64));
    mx.w = fmaxf(mx.w, __shfl_xor(mx.w, m, 64));
  }

  // ---- fused pass B+C: exp-sum partials + unnormalized aggregation
  float4 smp = make_float4(0.f, 0.f, 0.f, 0.f);  // per-lane exp-sum partials
  float2 acc = make_float2(0.f, 0.f);            // un-normalized agg (2 cols)
  const float2* Wx2 = (const float2*)Wx;
  for (int c0 = 0; c0 < deg; c0 += 64) {
    const int m = min(64, deg - c0);
    if (lane < m) {
      int src = csr_src[base + c0 + lane];
      float4 si = *(const float4*)(s_i + (size_t)src * 4);
      float4 p;
      p.x = __expf(lrelu(si.x + sj.x) - mx.x);
      p.y = __expf(lrelu(si.y + sj.y) - mx.y);
      p.z = __expf(lrelu(si.z + sj.z) - mx.z);
      p.w = __expf(lrelu(si.w + sj.w) - mx.w);
      smp.x += p.x; smp.y += p.y; smp.z += p.z; smp.w += p.w;
      lsrc[wv][lane] = src;
      *(float4*)&lp[wv][lane][0] = p;
    }
    // same-wave LDS write->read: drain LDS queue + compiler fence
    asm volatile("s_waitcnt lgkmcnt(0)" ::: "memory");
    int k = 0;
    for (; k + 4 <= m; k += 4) {
      int s0 = lsrc[wv][k + 0], s1 = lsrc[wv][k + 1];
      int s2 = lsrc[wv][k + 2], s3 = lsrc[wv][k + 3];
      float p0 = lp[wv][k + 0][h], p1 = lp[wv][k + 1][h];
      float p2 = lp[wv][k + 2][h], p3 = lp[wv][k + 3][h];
      float2 w0 = Wx2[(size_t)s0 * 64 + lane];
      float2 w1 = Wx2[(size_t)s1 * 64 + lane];
      float2 w2 = Wx2[(size_t)s2 * 64 + lane];
      float2 w3 = Wx2[(size_t)s3 * 64 + lane];
      acc.x += p0 * w0.x; acc.y += p0 * w0.y;
      acc.x += p1 * w1.x; acc.y += p1 * w1.y;
      acc.x += p2 * w2.x; acc.y += p2 * w2.y;
      acc.x += p3 * w3.x; acc.y += p3 * w3.y;
    }
    for (; k < m; ++k) {
      int s = lsrc[wv][k];
      float pv = lp[wv][k][h];
      float2 w = Wx2[(size_t)s * 64 + lane];
      acc.x += pv * w.x; acc.y += pv * w.y;
    }
  }
#pragma unroll
  for (int m = 1; m < 64; m <<= 1) {
    smp.x += __shfl_xor(smp.x, m, 64);
    smp.y += __shfl_xor(smp.y, m, 64);
    smp.z += __shfl_xor(smp.z, m, 64);
    smp.w += __shfl_xor(smp.w, m, 64);
  }
  float sh = (h & 2) ? ((h & 1) ? smp.w : smp.z) : ((h & 1) ? smp.y : smp.x);
  const float inv = 1.f / (sh + 1e-16f);
  ((float2*)agg)[(size_t)nd * 64 + lane] = make_float2(acc.x * inv, acc.y * inv);
}

// ---------------------------------------------------------------- GEMM 2
__global__ void k_gemm2(float* __restrict__ io, const float* __restrict__ ow,
                        const float* __restrict__ ob, int n) {
  const int lane = threadIdx.x & 63;
  const int gw = blockIdx.x * (blockDim.x >> 6) + (threadIdx.x >> 6);
  const int r0 = gw * 8;
  if (r0 >= n) return;
  const float2* W2 = (const float2*)ow;
  float2 acc[8];
#pragma unroll
  for (int r = 0; r < 8; ++r) acc[r] = make_float2(0.f, 0.f);
  const float* xb = io + (size_t)r0 * 128;
  for (int k = 0; k < 128; k += 4) {
    float2 w0 = W2[(k + 0) * 64 + lane];
    float2 w1 = W2[(k + 1) * 64 + lane];
    float2 w2 = W2[(k + 2) * 64 + lane];
    float2 w3 = W2[(k + 3) * 64 + lane];
#pragma unroll
    for (int r = 0; r < 8; ++r) {
      float4 xv = *(const float4*)(xb + r * 128 + k);
      acc[r].x += xv.x * w0.x; acc[r].y += xv.x * w0.y;
      acc[r].x += xv.y * w1.x; acc[r].y += xv.y * w1.y;
      acc[r].x += xv.z * w2.x; acc[r].y += xv.z * w2.y;
      acc[r].x += xv.w * w3.x; acc[r].y += xv.w * w3.y;
    }
  }
  const float2 b2 = ((const float2*)ob)[lane];
#pragma unroll
  for (int r = 0; r < 8; ++r) {
    float ox = acc[r].x + b2.x;
    float oy = acc[r].y + b2.y;
    ox = ox > 0.f ? ox : expm1f(ox);
    oy = oy > 0.f ? oy : expm1f(oy);
    ((float2*)io)[(size_t)(r0 + r) * 64 + lane] = make_float2(ox, oy);
  }
}

// ---------------------------------------------------------------- launch
extern "C" void kernel_launch(void* const* d_in, const int* in_sizes, int n_in,
                              void* d_out, int out_size, void* d_ws, size_t ws_size,
                              hipStream_t stream) {
  const float* x    = (const float*)d_in[0];
  const int*   edges = (const int*)d_in[1];   // [2,E] int (src row then dst row)
  const float* W    = (const float*)d_in[2];
  const float* attn = (const float*)d_in[3];
  const float* ow   = (const float*)d_in[4];
  const float* ob   = (const float*)d_in[5];
  const int n = in_sizes[0] / 128;
  const int E = in_sizes[1] / 2;
  float* out = (float*)d_out;

  char* wp = (char*)d_ws;
  auto alloc = [&](size_t bytes) {
    char* p = wp;
    wp += (bytes + 255) & ~(size_t)255;
    return p;
  };
  float* Wx     = (float*)alloc((size_t)n * 128 * 4);
  float* s_i    = (float*)alloc((size_t)n * 4 * 4);
  float* s_j    = (float*)alloc((size_t)n * 4 * 4);
  int*   cnts   = (int*)alloc((size_t)n * 4);
  int*   offs   = (int*)alloc((size_t)n * 4);
  int*   cursor = (int*)alloc((size_t)n * 4);
  int*   csr    = (int*)alloc((size_t)E * 4);
  const int nb = (n + 1023) / 1024;
  int*   part   = (int*)alloc((size_t)nb * 4);

  hipMemsetAsync(cnts, 0, (size_t)n * 4, stream);

  dim3 blk(256);
  const int gw1 = (n + 7) / 8;  // waves for the two GEMMs (8 rows/wave)
  k_gemm1<<<(gw1 + 3) / 4, blk, 0, stream>>>(x, W, attn, Wx, s_i, s_j, n);
  k_hist<<<(E + 255) / 256, blk, 0, stream>>>(edges + E, cnts, E);
  k_scan1<<<nb, blk, 0, stream>>>(cnts, part, n);
  k_scan2<<<1, 64, 0, stream>>>(part, nb);
  k_scan3<<<nb, blk, 0, stream>>>(cnts, part, offs, cursor, n);
  k_fill<<<(E + 255) / 256, blk, 0, stream>>>(edges, cursor, csr, E);
  k_agg<<<(n + AGG_WPB - 1) / AGG_WPB, blk, 0, stream>>>(Wx, s_i, s_j, offs, cnts, csr, out, n);
  k_gemm2<<<(gw1 + 3) / 4, blk, 0, stream>>>(out, ow, ob, n);
}

// Round 3
// 174.529 us; speedup vs baseline: 2.4483x; 1.9735x over previous
//
#include <hip/hip_runtime.h>
#include <math.h>

// GAT layer: N=50000 nodes, E=800000 edges, D_IN=D_OUT=128, H=4, D_H=32
//
// Pipeline:
//   k_mkfrag : pre-pack W / out_w (f32 row-major) into bf16 MFMA B-fragments
//   k_gemm1  : Wx(bf16) = x @ W via mfma_f32_16x16x32_bf16, fused per-node
//              attention scores s_i, s_j (f32, from f32 accumulators)
//   k_hist   : in-degree histogram by dst
//   k_scan*  : 3-phase exclusive prefix sum -> CSR offsets
//   k_fill   : scatter edge src indices into CSR slots
//   k_agg    : per-node pull softmax+aggregate (single pass, no max subtract:
//              |e| <~ 10 so exp is safe; ratios identical) -> agg bf16
//   k_gemm2  : out = elu(agg @ out_w + out_b) via MFMA, f32 out
//
// MFMA fragment maps (16x16x32 bf16):
//   A(lane,j) = A[m = lane&15][k = (lane>>4)*8 + j]
//   B(lane,j) = B[k = (lane>>4)*8 + j][nn = lane&15]
//   D(lane,r) = D[m = (lane>>4)*4 + r][nn = lane&15]   (HW-verified)
// Correctness is invariant to the true HW k-ordering because A and B use the
// same (group,elem)->k map (dot products are permutation-invariant).

typedef __attribute__((ext_vector_type(8))) short short8;
typedef __attribute__((ext_vector_type(4))) float f32x4;

__device__ __forceinline__ float lrelu(float v) { return v >= 0.f ? v : 0.2f * v; }

__device__ __forceinline__ unsigned short f2bf(float f) {  // RNE f32 -> bf16
  unsigned int u = __float_as_uint(f);
  u += 0x7FFFu + ((u >> 16) & 1u);
  return (unsigned short)(u >> 16);
}
__device__ __forceinline__ float bflo(unsigned int w) { return __uint_as_float(w << 16); }
__device__ __forceinline__ float bfhi(unsigned int w) { return __uint_as_float(w & 0xFFFF0000u); }

// ---------------------------------------------------------------- frag pack
// F[((ks*8+nt)*64+lane)*8 + j] = bf16( M[ks*32+(lane>>4)*8+j][nt*16+(lane&15)] )
__global__ void k_mkfrag(const float* __restrict__ M, unsigned short* __restrict__ F) {
  const int t = blockIdx.x * 256 + threadIdx.x;
  if (t >= 2048) return;
  const int lane = t & 63;
  const int nt = (t >> 6) & 7;
  const int ks = t >> 9;
  const int k0 = ks * 32 + (lane >> 4) * 8;
  const int col = nt * 16 + (lane & 15);
  unsigned short e[8];
#pragma unroll
  for (int j = 0; j < 8; ++j) e[j] = f2bf(M[(k0 + j) * 128 + col]);
  short8 v;
#pragma unroll
  for (int j = 0; j < 8; ++j) v[j] = (short)e[j];
  *(short8*)(F + (size_t)t * 8) = v;
}

// ---------------------------------------------------------------- GEMM 1
// One wave = 16-row strip. acc[nt] (nt=0..7) covers cols nt*16..nt*16+15.
__global__ void k_gemm1(const float* __restrict__ x, const unsigned short* __restrict__ wf,
                        const float* __restrict__ attn, unsigned int* __restrict__ Wxb,
                        float* __restrict__ s_i, float* __restrict__ s_j, int n) {
  const int lane = threadIdx.x & 63;
  const int gw = blockIdx.x * (blockDim.x >> 6) + (threadIdx.x >> 6);
  const int r0 = gw * 16;
  if (r0 >= n) return;
  const int g = lane >> 4, c = lane & 15;

  f32x4 acc[8];
#pragma unroll
  for (int nt = 0; nt < 8; ++nt) acc[nt] = (f32x4){0.f, 0.f, 0.f, 0.f};

  const int arow = min(r0 + c, n - 1);
#pragma unroll
  for (int ks = 0; ks < 4; ++ks) {
    const float* xr = x + (size_t)arow * 128 + ks * 32 + g * 8;
    float4 v0 = *(const float4*)xr;
    float4 v1 = *(const float4*)(xr + 4);
    short8 af;
    af[0] = (short)f2bf(v0.x); af[1] = (short)f2bf(v0.y);
    af[2] = (short)f2bf(v0.z); af[3] = (short)f2bf(v0.w);
    af[4] = (short)f2bf(v1.x); af[5] = (short)f2bf(v1.y);
    af[6] = (short)f2bf(v1.z); af[7] = (short)f2bf(v1.w);
#pragma unroll
    for (int nt = 0; nt < 8; ++nt) {
      short8 bf = *(const short8*)(wf + ((size_t)(ks * 8 + nt) * 64 + lane) * 8);
      acc[nt] = __builtin_amdgcn_mfma_f32_16x16x32_bf16(af, bf, acc[nt], 0, 0, 0);
    }
  }

  // ---- write Wx as bf16 packed pairs (even lanes: tiles 0..3, odd: 4..7)
  const int odd = c & 1;
#pragma unroll
  for (int r = 0; r < 4; ++r) {
    const int row = r0 + g * 4 + r;
    if (row >= n) continue;
    unsigned int* dst = Wxb + (size_t)row * 64;
#pragma unroll
    for (int ntp = 0; ntp < 4; ++ntp) {
      float ve = acc[ntp][r], vo = acc[ntp + 4][r];
      float vex = __shfl_xor(ve, 1, 64);
      float vox = __shfl_xor(vo, 1, 64);
      unsigned int lo = odd ? f2bf(vox) : f2bf(ve);
      unsigned int hi = odd ? f2bf(vo) : f2bf(vex);
      const int nt = odd ? ntp + 4 : ntp;
      dst[nt * 8 + (c >> 1)] = lo | (hi << 16);
    }
  }

  // ---- fused attention scores (f32 accumulators)
  float aiv[8], ajv[8];
#pragma unroll
  for (int nt = 0; nt < 8; ++nt) {
    const int hh = nt >> 1, ch = (nt & 1) * 16 + c;
    aiv[nt] = attn[hh * 64 + ch];
    ajv[nt] = attn[hh * 64 + 32 + ch];
  }
#pragma unroll
  for (int r = 0; r < 4; ++r) {
    float pih[4], pjh[4];
#pragma unroll
    for (int h = 0; h < 4; ++h) {
      pih[h] = acc[2 * h][r] * aiv[2 * h] + acc[2 * h + 1][r] * aiv[2 * h + 1];
      pjh[h] = acc[2 * h][r] * ajv[2 * h] + acc[2 * h + 1][r] * ajv[2 * h + 1];
    }
#pragma unroll
    for (int m = 1; m < 16; m <<= 1) {
#pragma unroll
      for (int h = 0; h < 4; ++h) {
        pih[h] += __shfl_xor(pih[h], m, 64);
        pjh[h] += __shfl_xor(pjh[h], m, 64);
      }
    }
    const int row = r0 + g * 4 + r;
    if (c == 0 && row < n) {
#pragma unroll
      for (int h = 0; h < 4; ++h) {
        s_i[(size_t)row * 4 + h] = pih[h];
        s_j[(size_t)row * 4 + h] = pjh[h];
      }
    }
  }
}

// ---------------------------------------------------------------- histogram
__global__ void k_hist(const int* __restrict__ dst, int* __restrict__ cnts, int E) {
  int e = blockIdx.x * 256 + threadIdx.x;
  if (e < E) atomicAdd(&cnts[dst[e]], 1);
}

// ---------------------------------------------------------------- scan (3 phases)
__global__ void k_scan1(const int* __restrict__ cnts, int* __restrict__ part, int n) {
  __shared__ int ws[4];
  const int t = threadIdx.x, lane = t & 63, wv = t >> 6;
  const int base = blockIdx.x * 1024 + t * 4;
  int s = 0;
  if (base + 3 < n) {
    int4 v = *(const int4*)(cnts + base);
    s = v.x + v.y + v.z + v.w;
  } else {
#pragma unroll
    for (int i = 0; i < 4; ++i) if (base + i < n) s += cnts[base + i];
  }
#pragma unroll
  for (int m = 1; m < 64; m <<= 1) s += __shfl_xor(s, m, 64);
  if (lane == 0) ws[wv] = s;
  __syncthreads();
  if (t == 0) part[blockIdx.x] = ws[0] + ws[1] + ws[2] + ws[3];
}

__global__ void k_scan2(int* __restrict__ part, int nb) {
  const int lane = threadIdx.x;
  int carry = 0;
  for (int b = 0; b < nb; b += 64) {
    const int i = b + lane;
    int v = (i < nb) ? part[i] : 0;
    int incl = v;
#pragma unroll
    for (int m = 1; m < 64; m <<= 1) {
      int t = __shfl_up(incl, m, 64);
      if (lane >= m) incl += t;
    }
    if (i < nb) part[i] = carry + incl - v;
    carry += __shfl(incl, 63, 64);
  }
}

__global__ void k_scan3(const int* __restrict__ cnts, const int* __restrict__ part,
                        int* __restrict__ offs, int* __restrict__ cursor, int n) {
  __shared__ int ws[4];
  const int t = threadIdx.x, lane = t & 63, wv = t >> 6;
  const int base = blockIdx.x * 1024 + t * 4;
  int4 v = make_int4(0, 0, 0, 0);
  if (base + 3 < n) {
    v = *(const int4*)(cnts + base);
  } else {
    if (base + 0 < n) v.x = cnts[base + 0];
    if (base + 1 < n) v.y = cnts[base + 1];
    if (base + 2 < n) v.z = cnts[base + 2];
    if (base + 3 < n) v.w = cnts[base + 3];
  }
  const int s = v.x + v.y + v.z + v.w;
  int incl = s;
#pragma unroll
  for (int m = 1; m < 64; m <<= 1) {
    int tt = __shfl_up(incl, m, 64);
    if (lane >= m) incl += tt;
  }
  if (lane == 63) ws[wv] = incl;
  __syncthreads();
  int woff = 0;
  for (int p = 0; p < wv; ++p) woff += ws[p];
  const int excl = part[blockIdx.x] + woff + incl - s;
  int4 o;
  o.x = excl; o.y = o.x + v.x; o.z = o.y + v.y; o.w = o.z + v.z;
  if (base + 3 < n) {
    *(int4*)(offs + base) = o;
    *(int4*)(cursor + base) = o;
  } else {
    if (base + 0 < n) { offs[base + 0] = o.x; cursor[base + 0] = o.x; }
    if (base + 1 < n) { offs[base + 1] = o.y; cursor[base + 1] = o.y; }
    if (base + 2 < n) { offs[base + 2] = o.z; cursor[base + 2] = o.z; }
    if (base + 3 < n) { offs[base + 3] = o.w; cursor[base + 3] = o.w; }
  }
}

// ---------------------------------------------------------------- CSR fill
__global__ void k_fill(const int* __restrict__ edges, int* __restrict__ cursor,
                       int* __restrict__ csr_src, int E) {
  int e = blockIdx.x * 256 + threadIdx.x;
  if (e < E) {
    int d = edges[E + e];
    int pos = atomicAdd(&cursor[d], 1);
    csr_src[pos] = edges[e];
  }
}

// ---------------------------------------------------------------- aggregate
// One wave per destination node; single fused pass (no max subtraction).
#define AGG_WPB 4
__global__ void k_agg(const unsigned int* __restrict__ Wxb, const float* __restrict__ s_i,
                      const float* __restrict__ s_j, const int* __restrict__ offs,
                      const int* __restrict__ cnts, const int* __restrict__ csr_src,
                      unsigned int* __restrict__ aggb, int n) {
  __shared__ int   lsrc[AGG_WPB][64];
  __shared__ float lp[AGG_WPB][64][4];
  const int lane = threadIdx.x & 63;
  const int wv = threadIdx.x >> 6;
  const int nd = blockIdx.x * AGG_WPB + wv;
  if (nd >= n) return;
  const int base = offs[nd];
  const int deg = cnts[nd];
  const float4 sj = *(const float4*)(s_j + (size_t)nd * 4);
  const int h = lane >> 4;

  float4 smp = make_float4(0.f, 0.f, 0.f, 0.f);  // per-lane exp-sum partials
  float2 acc = make_float2(0.f, 0.f);            // un-normalized agg (2 cols)
  for (int c0 = 0; c0 < deg; c0 += 64) {
    const int m = min(64, deg - c0);
    if (lane < m) {
      int src = csr_src[base + c0 + lane];
      float4 si = *(const float4*)(s_i + (size_t)src * 4);
      float4 p;
      p.x = __expf(lrelu(si.x + sj.x));
      p.y = __expf(lrelu(si.y + sj.y));
      p.z = __expf(lrelu(si.z + sj.z));
      p.w = __expf(lrelu(si.w + sj.w));
      smp.x += p.x; smp.y += p.y; smp.z += p.z; smp.w += p.w;
      lsrc[wv][lane] = src;
      *(float4*)&lp[wv][lane][0] = p;
    }
    asm volatile("s_waitcnt lgkmcnt(0)" ::: "memory");  // same-wave LDS RAW
    int k = 0;
    for (; k + 4 <= m; k += 4) {
      int s0 = lsrc[wv][k + 0], s1 = lsrc[wv][k + 1];
      int s2 = lsrc[wv][k + 2], s3 = lsrc[wv][k + 3];
      float p0 = lp[wv][k + 0][h], p1 = lp[wv][k + 1][h];
      float p2 = lp[wv][k + 2][h], p3 = lp[wv][k + 3][h];
      unsigned int w0 = Wxb[(size_t)s0 * 64 + lane];
      unsigned int w1 = Wxb[(size_t)s1 * 64 + lane];
      unsigned int w2 = Wxb[(size_t)s2 * 64 + lane];
      unsigned int w3 = Wxb[(size_t)s3 * 64 + lane];
      acc.x += p0 * bflo(w0); acc.y += p0 * bfhi(w0);
      acc.x += p1 * bflo(w1); acc.y += p1 * bfhi(w1);
      acc.x += p2 * bflo(w2); acc.y += p2 * bfhi(w2);
      acc.x += p3 * bflo(w3); acc.y += p3 * bfhi(w3);
    }
    for (; k < m; ++k) {
      int s = lsrc[wv][k];
      float pv = lp[wv][k][h];
      unsigned int w = Wxb[(size_t)s * 64 + lane];
      acc.x += pv * bflo(w); acc.y += pv * bfhi(w);
    }
  }
#pragma unroll
  for (int m = 1; m < 64; m <<= 1) {
    smp.x += __shfl_xor(smp.x, m, 64);
    smp.y += __shfl_xor(smp.y, m, 64);
    smp.z += __shfl_xor(smp.z, m, 64);
    smp.w += __shfl_xor(smp.w, m, 64);
  }
  float sh = (h & 2) ? ((h & 1) ? smp.w : smp.z) : ((h & 1) ? smp.y : smp.x);
  const float inv = 1.f / (sh + 1e-16f);
  unsigned int lo = f2bf(acc.x * inv), hi = f2bf(acc.y * inv);
  aggb[(size_t)nd * 64 + lane] = lo | (hi << 16);
}

// ---------------------------------------------------------------- GEMM 2
__global__ void k_gemm2(const unsigned int* __restrict__ aggb,
                        const unsigned short* __restrict__ owf,
                        const float* __restrict__ ob, float* __restrict__ out, int n) {
  const int lane = threadIdx.x & 63;
  const int gw = blockIdx.x * (blockDim.x >> 6) + (threadIdx.x >> 6);
  const int r0 = gw * 16;
  if (r0 >= n) return;
  const int g = lane >> 4, c = lane & 15;

  f32x4 acc[8];
#pragma unroll
  for (int nt = 0; nt < 8; ++nt) acc[nt] = (f32x4){0.f, 0.f, 0.f, 0.f};

  const int arow = min(r0 + c, n - 1);
#pragma unroll
  for (int ks = 0; ks < 4; ++ks) {
    // 8 consecutive bf16 = 4 uints at col ks*32 + g*8
    const unsigned int* ar = aggb + (size_t)arow * 64 + ks * 16 + g * 4;
    uint4 av = *(const uint4*)ar;
    short8 af;
    af[0] = (short)(av.x & 0xFFFF); af[1] = (short)(av.x >> 16);
    af[2] = (short)(av.y & 0xFFFF); af[3] = (short)(av.y >> 16);
    af[4] = (short)(av.z & 0xFFFF); af[5] = (short)(av.z >> 16);
    af[6] = (short)(av.w & 0xFFFF); af[7] = (short)(av.w >> 16);
#pragma unroll
    for (int nt = 0; nt < 8; ++nt) {
      short8 bf = *(const short8*)(owf + ((size_t)(ks * 8 + nt) * 64 + lane) * 8);
      acc[nt] = __builtin_amdgcn_mfma_f32_16x16x32_bf16(af, bf, acc[nt], 0, 0, 0);
    }
  }

#pragma unroll
  for (int r = 0; r < 4; ++r) {
    const int row = r0 + g * 4 + r;
    if (row >= n) continue;
    float* dst = out + (size_t)row * 128;
#pragma unroll
    for (int nt = 0; nt < 8; ++nt) {
      float v = acc[nt][r] + ob[nt * 16 + c];
      v = v > 0.f ? v : expm1f(v);
      dst[nt * 16 + c] = v;
    }
  }
}

// ---------------------------------------------------------------- launch
extern "C" void kernel_launch(void* const* d_in, const int* in_sizes, int n_in,
                              void* d_out, int out_size, void* d_ws, size_t ws_size,
                              hipStream_t stream) {
  const float* x    = (const float*)d_in[0];
  const int*   edges = (const int*)d_in[1];   // [2,E] (src row then dst row)
  const float* W    = (const float*)d_in[2];
  const float* attn = (const float*)d_in[3];
  const float* ow   = (const float*)d_in[4];
  const float* ob   = (const float*)d_in[5];
  const int n = in_sizes[0] / 128;
  const int E = in_sizes[1] / 2;
  float* out = (float*)d_out;

  char* wp = (char*)d_ws;
  auto alloc = [&](size_t bytes) {
    char* p = wp;
    wp += (bytes + 255) & ~(size_t)255;
    return p;
  };
  unsigned short* wf  = (unsigned short*)alloc(2048 * 8 * 2);
  unsigned short* owf = (unsigned short*)alloc(2048 * 8 * 2);
  unsigned int*   Wxb = (unsigned int*)alloc((size_t)n * 64 * 4);
  unsigned int*   agb = (unsigned int*)alloc((size_t)n * 64 * 4);
  float* s_i    = (float*)alloc((size_t)n * 4 * 4);
  float* s_j    = (float*)alloc((size_t)n * 4 * 4);
  int*   cnts   = (int*)alloc((size_t)n * 4);
  int*   offs   = (int*)alloc((size_t)n * 4);
  int*   cursor = (int*)alloc((size_t)n * 4);
  int*   csr    = (int*)alloc((size_t)E * 4);
  const int nb = (n + 1023) / 1024;
  int*   part   = (int*)alloc((size_t)nb * 4);

  hipMemsetAsync(cnts, 0, (size_t)n * 4, stream);

  dim3 blk(256);
  k_mkfrag<<<8, blk, 0, stream>>>(W, wf);
  k_mkfrag<<<8, blk, 0, stream>>>(ow, owf);
  const int strips = (n + 15) / 16;
  k_gemm1<<<(strips + 3) / 4, blk, 0, stream>>>(x, wf, attn, Wxb, s_i, s_j, n);
  k_hist<<<(E + 255) / 256, blk, 0, stream>>>(edges + E, cnts, E);
  k_scan1<<<nb, blk, 0, stream>>>(cnts, part, n);
  k_scan2<<<1, 64, 0, stream>>>(part, nb);
  k_scan3<<<nb, blk, 0, stream>>>(cnts, part, offs, cursor, n);
  k_fill<<<(E + 255) / 256, blk, 0, stream>>>(edges, cursor, csr, E);
  k_agg<<<(n + AGG_WPB - 1) / AGG_WPB, blk, 0, stream>>>(Wxb, s_i, s_j, offs, cnts, csr, agb, n);
  k_gemm2<<<(strips + 3) / 4, blk, 0, stream>>>(agb, owf, ob, out, n);
}

// Round 4
// 121.991 us; speedup vs baseline: 3.5027x; 1.4307x over previous
//
#include <hip/hip_runtime.h>
#include <math.h>

// GAT layer: N=50000 nodes, E=800000 edges, D_IN=D_OUT=128, H=4, D_H=32
//
// Pipeline:
//   k_mkfrag : pre-pack W / out_w (f32 row-major) into bf16 MFMA B-fragments
//   k_gemm1  : Wx(bf16) = x @ W via mfma_f32_16x16x32_bf16, fused per-node
//              attention scores s_i, s_j
//   CSR build (2-level counting sort on dst>>8; N<65536 so (src,dst) packs u32):
//     k_bcnt : bucket histogram (LDS pre-agg)
//     k_bscan: 1-block scan of bucket counts -> bases + cursors
//     k_bin1 : block-local counting sort, per-(block,bucket) run claim, burst
//              writes of packed edges into bucket-contiguous tmp
//     k_bin2 : one block per bucket: node counts + scan (emits offs/cnts) +
//              placement — all scatter is block-private (single XCD L2)
//   k_agg    : per-node pull softmax+aggregate (single pass, no max subtract)
//   k_gemm2  : out = elu(agg @ out_w + out_b) via MFMA, f32 out

typedef __attribute__((ext_vector_type(8))) short short8;
typedef __attribute__((ext_vector_type(4))) float f32x4;

__device__ __forceinline__ float lrelu(float v) { return v >= 0.f ? v : 0.2f * v; }

__device__ __forceinline__ unsigned short f2bf(float f) {  // RNE f32 -> bf16
  unsigned int u = __float_as_uint(f);
  u += 0x7FFFu + ((u >> 16) & 1u);
  return (unsigned short)(u >> 16);
}
__device__ __forceinline__ float bflo(unsigned int w) { return __uint_as_float(w << 16); }
__device__ __forceinline__ float bfhi(unsigned int w) { return __uint_as_float(w & 0xFFFF0000u); }

// ---------------------------------------------------------------- frag pack
__global__ void k_mkfrag(const float* __restrict__ M, unsigned short* __restrict__ F) {
  const int t = blockIdx.x * 256 + threadIdx.x;
  if (t >= 2048) return;
  const int lane = t & 63;
  const int nt = (t >> 6) & 7;
  const int ks = t >> 9;
  const int k0 = ks * 32 + (lane >> 4) * 8;
  const int col = nt * 16 + (lane & 15);
  short8 v;
#pragma unroll
  for (int j = 0; j < 8; ++j) v[j] = (short)f2bf(M[(k0 + j) * 128 + col]);
  *(short8*)(F + (size_t)t * 8) = v;
}

// ---------------------------------------------------------------- GEMM 1
__global__ void k_gemm1(const float* __restrict__ x, const unsigned short* __restrict__ wf,
                        const float* __restrict__ attn, unsigned int* __restrict__ Wxb,
                        float* __restrict__ s_i, float* __restrict__ s_j, int n) {
  const int lane = threadIdx.x & 63;
  const int gw = blockIdx.x * (blockDim.x >> 6) + (threadIdx.x >> 6);
  const int r0 = gw * 16;
  if (r0 >= n) return;
  const int g = lane >> 4, c = lane & 15;

  f32x4 acc[8];
#pragma unroll
  for (int nt = 0; nt < 8; ++nt) acc[nt] = (f32x4){0.f, 0.f, 0.f, 0.f};

  const int arow = min(r0 + c, n - 1);
#pragma unroll
  for (int ks = 0; ks < 4; ++ks) {
    const float* xr = x + (size_t)arow * 128 + ks * 32 + g * 8;
    float4 v0 = *(const float4*)xr;
    float4 v1 = *(const float4*)(xr + 4);
    short8 af;
    af[0] = (short)f2bf(v0.x); af[1] = (short)f2bf(v0.y);
    af[2] = (short)f2bf(v0.z); af[3] = (short)f2bf(v0.w);
    af[4] = (short)f2bf(v1.x); af[5] = (short)f2bf(v1.y);
    af[6] = (short)f2bf(v1.z); af[7] = (short)f2bf(v1.w);
#pragma unroll
    for (int nt = 0; nt < 8; ++nt) {
      short8 bf = *(const short8*)(wf + ((size_t)(ks * 8 + nt) * 64 + lane) * 8);
      acc[nt] = __builtin_amdgcn_mfma_f32_16x16x32_bf16(af, bf, acc[nt], 0, 0, 0);
    }
  }

  const int odd = c & 1;
#pragma unroll
  for (int r = 0; r < 4; ++r) {
    const int row = r0 + g * 4 + r;
    if (row >= n) continue;
    unsigned int* dst = Wxb + (size_t)row * 64;
#pragma unroll
    for (int ntp = 0; ntp < 4; ++ntp) {
      float ve = acc[ntp][r], vo = acc[ntp + 4][r];
      float vex = __shfl_xor(ve, 1, 64);
      float vox = __shfl_xor(vo, 1, 64);
      unsigned int lo = odd ? f2bf(vox) : f2bf(ve);
      unsigned int hi = odd ? f2bf(vo) : f2bf(vex);
      const int nt = odd ? ntp + 4 : ntp;
      dst[nt * 8 + (c >> 1)] = lo | (hi << 16);
    }
  }

  float aiv[8], ajv[8];
#pragma unroll
  for (int nt = 0; nt < 8; ++nt) {
    const int hh = nt >> 1, ch = (nt & 1) * 16 + c;
    aiv[nt] = attn[hh * 64 + ch];
    ajv[nt] = attn[hh * 64 + 32 + ch];
  }
#pragma unroll
  for (int r = 0; r < 4; ++r) {
    float pih[4], pjh[4];
#pragma unroll
    for (int h = 0; h < 4; ++h) {
      pih[h] = acc[2 * h][r] * aiv[2 * h] + acc[2 * h + 1][r] * aiv[2 * h + 1];
      pjh[h] = acc[2 * h][r] * ajv[2 * h] + acc[2 * h + 1][r] * ajv[2 * h + 1];
    }
#pragma unroll
    for (int m = 1; m < 16; m <<= 1) {
#pragma unroll
      for (int h = 0; h < 4; ++h) {
        pih[h] += __shfl_xor(pih[h], m, 64);
        pjh[h] += __shfl_xor(pjh[h], m, 64);
      }
    }
    const int row = r0 + g * 4 + r;
    if (c == 0 && row < n) {
#pragma unroll
      for (int h = 0; h < 4; ++h) {
        s_i[(size_t)row * 4 + h] = pih[h];
        s_j[(size_t)row * 4 + h] = pjh[h];
      }
    }
  }
}

// ---------------------------------------------------------------- CSR build
#define BIN_VPT 16          // edges per thread; 4096 edges per 256-thread block

// bucket histogram (bucket = dst >> 8)
__global__ void k_bcnt(const int* __restrict__ dst, int* __restrict__ gcnt, int E) {
  __shared__ int lc[256];
  lc[threadIdx.x] = 0;
  __syncthreads();
  const int base = blockIdx.x * (256 * BIN_VPT);
#pragma unroll
  for (int j = 0; j < BIN_VPT; ++j) {
    int e = base + j * 256 + threadIdx.x;
    if (e < E) atomicAdd(&lc[((unsigned int)dst[e]) >> 8], 1);
  }
  __syncthreads();
  int c = lc[threadIdx.x];
  if (c) atomicAdd(&gcnt[threadIdx.x], c);
}

// 1-block exclusive scan of 256 bucket counts -> gcur (cursors) + bstart
__global__ void k_bscan(const int* __restrict__ gcnt, int* __restrict__ gcur,
                        int* __restrict__ bstart) {
  __shared__ int ws[4];
  const int t = threadIdx.x, lane = t & 63, wv = t >> 6;
  const int v = gcnt[t];
  int incl = v;
#pragma unroll
  for (int m = 1; m < 64; m <<= 1) {
    int x = __shfl_up(incl, m, 64);
    if (lane >= m) incl += x;
  }
  if (lane == 63) ws[wv] = incl;
  __syncthreads();
  int woff = 0;
  for (int p = 0; p < wv; ++p) woff += ws[p];
  const int excl = woff + incl - v;
  gcur[t] = excl;
  bstart[t] = excl;
}

// block-local counting sort into bucket-contiguous tmp (packed src | dst<<16)
__global__ void k_bin1(const int* __restrict__ edges, int* __restrict__ gcur,
                       unsigned int* __restrict__ tmp, int E) {
  __shared__ int lcnt[256];
  __shared__ int lbase[256];
  lcnt[threadIdx.x] = 0;
  __syncthreads();
  const int base = blockIdx.x * (256 * BIN_VPT);
  unsigned int pv[BIN_VPT];
  int rk[BIN_VPT];
#pragma unroll
  for (int j = 0; j < BIN_VPT; ++j) {
    int e = base + j * 256 + threadIdx.x;
    if (e < E) {
      unsigned int s = (unsigned int)edges[e];
      unsigned int d = (unsigned int)edges[E + e];
      pv[j] = s | (d << 16);
      rk[j] = atomicAdd(&lcnt[d >> 8], 1);
    } else {
      pv[j] = 0u;
      rk[j] = -1;
    }
  }
  __syncthreads();
  const int c = lcnt[threadIdx.x];
  lbase[threadIdx.x] = c ? atomicAdd(&gcur[threadIdx.x], c) : 0;
  __syncthreads();
#pragma unroll
  for (int j = 0; j < BIN_VPT; ++j) {
    if (rk[j] >= 0) {
      const int b = pv[j] >> 24;  // dst >> 8
      tmp[lbase[b] + rk[j]] = pv[j];
    }
  }
}

// one block per bucket: node counts -> scan (offs/cnts) -> placement
__global__ void k_bin2(const unsigned int* __restrict__ tmp, const int* __restrict__ bstart,
                       const int* __restrict__ gcnt, int* __restrict__ csr,
                       int* __restrict__ offs, int* __restrict__ cnts, int n) {
  __shared__ int nc[256];
  __shared__ int ws[4];
  const int b = blockIdx.x;
  const int base = bstart[b], cnt = gcnt[b];
  const int t = threadIdx.x, lane = t & 63, wv = t >> 6;
  nc[t] = 0;
  __syncthreads();
  for (int i = t; i < cnt; i += 256)
    atomicAdd(&nc[(tmp[base + i] >> 16) & 255], 1);
  __syncthreads();
  const int node = b * 256 + t;
  const int c = nc[t];
  if (node < n) cnts[node] = c;
  int incl = c;
#pragma unroll
  for (int m = 1; m < 64; m <<= 1) {
    int x = __shfl_up(incl, m, 64);
    if (lane >= m) incl += x;
  }
  if (lane == 63) ws[wv] = incl;
  __syncthreads();
  int woff = 0;
  for (int p = 0; p < wv; ++p) woff += ws[p];
  const int excl = woff + incl - c;
  if (node < n) offs[node] = base + excl;
  __syncthreads();           // everyone done reading nc from count phase
  nc[t] = excl;              // becomes local cursor
  __syncthreads();
  for (int i = t; i < cnt; i += 256) {
    unsigned int v = tmp[base + i];
    int pos = atomicAdd(&nc[(v >> 16) & 255], 1);
    csr[base + pos] = (int)(v & 0xFFFFu);
  }
}

// ---------------------------------------------------------------- aggregate
#define AGG_WPB 4
__global__ void k_agg(const unsigned int* __restrict__ Wxb, const float* __restrict__ s_i,
                      const float* __restrict__ s_j, const int* __restrict__ offs,
                      const int* __restrict__ cnts, const int* __restrict__ csr_src,
                      unsigned int* __restrict__ aggb, int n) {
  __shared__ int   lsrc[AGG_WPB][64];
  __shared__ float lp[AGG_WPB][64][4];
  const int lane = threadIdx.x & 63;
  const int wv = threadIdx.x >> 6;
  const int nd = blockIdx.x * AGG_WPB + wv;
  if (nd >= n) return;
  const int base = offs[nd];
  const int deg = cnts[nd];
  const float4 sj = *(const float4*)(s_j + (size_t)nd * 4);
  const int h = lane >> 4;

  float4 smp = make_float4(0.f, 0.f, 0.f, 0.f);
  float2 acc = make_float2(0.f, 0.f);
  for (int c0 = 0; c0 < deg; c0 += 64) {
    const int m = min(64, deg - c0);
    if (lane < m) {
      int src = csr_src[base + c0 + lane];
      float4 si = *(const float4*)(s_i + (size_t)src * 4);
      float4 p;
      p.x = __expf(lrelu(si.x + sj.x));
      p.y = __expf(lrelu(si.y + sj.y));
      p.z = __expf(lrelu(si.z + sj.z));
      p.w = __expf(lrelu(si.w + sj.w));
      smp.x += p.x; smp.y += p.y; smp.z += p.z; smp.w += p.w;
      lsrc[wv][lane] = src;
      *(float4*)&lp[wv][lane][0] = p;
    }
    asm volatile("s_waitcnt lgkmcnt(0)" ::: "memory");  // same-wave LDS RAW
    int k = 0;
    for (; k + 4 <= m; k += 4) {
      int s0 = lsrc[wv][k + 0], s1 = lsrc[wv][k + 1];
      int s2 = lsrc[wv][k + 2], s3 = lsrc[wv][k + 3];
      float p0 = lp[wv][k + 0][h], p1 = lp[wv][k + 1][h];
      float p2 = lp[wv][k + 2][h], p3 = lp[wv][k + 3][h];
      unsigned int w0 = Wxb[(size_t)s0 * 64 + lane];
      unsigned int w1 = Wxb[(size_t)s1 * 64 + lane];
      unsigned int w2 = Wxb[(size_t)s2 * 64 + lane];
      unsigned int w3 = Wxb[(size_t)s3 * 64 + lane];
      acc.x += p0 * bflo(w0); acc.y += p0 * bfhi(w0);
      acc.x += p1 * bflo(w1); acc.y += p1 * bfhi(w1);
      acc.x += p2 * bflo(w2); acc.y += p2 * bfhi(w2);
      acc.x += p3 * bflo(w3); acc.y += p3 * bfhi(w3);
    }
    for (; k < m; ++k) {
      int s = lsrc[wv][k];
      float pv = lp[wv][k][h];
      unsigned int w = Wxb[(size_t)s * 64 + lane];
      acc.x += pv * bflo(w); acc.y += pv * bfhi(w);
    }
  }
#pragma unroll
  for (int m = 1; m < 64; m <<= 1) {
    smp.x += __shfl_xor(smp.x, m, 64);
    smp.y += __shfl_xor(smp.y, m, 64);
    smp.z += __shfl_xor(smp.z, m, 64);
    smp.w += __shfl_xor(smp.w, m, 64);
  }
  float sh = (h & 2) ? ((h & 1) ? smp.w : smp.z) : ((h & 1) ? smp.y : smp.x);
  const float inv = 1.f / (sh + 1e-16f);
  unsigned int lo = f2bf(acc.x * inv), hi = f2bf(acc.y * inv);
  aggb[(size_t)nd * 64 + lane] = lo | (hi << 16);
}

// ---------------------------------------------------------------- GEMM 2
__global__ void k_gemm2(const unsigned int* __restrict__ aggb,
                        const unsigned short* __restrict__ owf,
                        const float* __restrict__ ob, float* __restrict__ out, int n) {
  const int lane = threadIdx.x & 63;
  const int gw = blockIdx.x * (blockDim.x >> 6) + (threadIdx.x >> 6);
  const int r0 = gw * 16;
  if (r0 >= n) return;
  const int g = lane >> 4, c = lane & 15;

  f32x4 acc[8];
#pragma unroll
  for (int nt = 0; nt < 8; ++nt) acc[nt] = (f32x4){0.f, 0.f, 0.f, 0.f};

  const int arow = min(r0 + c, n - 1);
#pragma unroll
  for (int ks = 0; ks < 4; ++ks) {
    const unsigned int* ar = aggb + (size_t)arow * 64 + ks * 16 + g * 4;
    uint4 av = *(const uint4*)ar;
    short8 af;
    af[0] = (short)(av.x & 0xFFFF); af[1] = (short)(av.x >> 16);
    af[2] = (short)(av.y & 0xFFFF); af[3] = (short)(av.y >> 16);
    af[4] = (short)(av.z & 0xFFFF); af[5] = (short)(av.z >> 16);
    af[6] = (short)(av.w & 0xFFFF); af[7] = (short)(av.w >> 16);
#pragma unroll
    for (int nt = 0; nt < 8; ++nt) {
      short8 bf = *(const short8*)(owf + ((size_t)(ks * 8 + nt) * 64 + lane) * 8);
      acc[nt] = __builtin_amdgcn_mfma_f32_16x16x32_bf16(af, bf, acc[nt], 0, 0, 0);
    }
  }

#pragma unroll
  for (int r = 0; r < 4; ++r) {
    const int row = r0 + g * 4 + r;
    if (row >= n) continue;
    float* dst = out + (size_t)row * 128;
#pragma unroll
    for (int nt = 0; nt < 8; ++nt) {
      float v = acc[nt][r] + ob[nt * 16 + c];
      v = v > 0.f ? v : expm1f(v);
      dst[nt * 16 + c] = v;
    }
  }
}

// ---------------------------------------------------------------- launch
extern "C" void kernel_launch(void* const* d_in, const int* in_sizes, int n_in,
                              void* d_out, int out_size, void* d_ws, size_t ws_size,
                              hipStream_t stream) {
  const float* x    = (const float*)d_in[0];
  const int*   edges = (const int*)d_in[1];   // [2,E] (src row then dst row)
  const float* W    = (const float*)d_in[2];
  const float* attn = (const float*)d_in[3];
  const float* ow   = (const float*)d_in[4];
  const float* ob   = (const float*)d_in[5];
  const int n = in_sizes[0] / 128;            // 50000 (< 65536: u32 edge pack)
  const int E = in_sizes[1] / 2;
  float* out = (float*)d_out;

  char* wp = (char*)d_ws;
  auto alloc = [&](size_t bytes) {
    char* p = wp;
    wp += (bytes + 255) & ~(size_t)255;
    return p;
  };
  unsigned short* wf  = (unsigned short*)alloc(2048 * 8 * 2);
  unsigned short* owf = (unsigned short*)alloc(2048 * 8 * 2);
  unsigned int*   Wxb = (unsigned int*)alloc((size_t)n * 64 * 4);
  unsigned int*   agb = (unsigned int*)alloc((size_t)n * 64 * 4);
  float* s_i    = (float*)alloc((size_t)n * 4 * 4);
  float* s_j    = (float*)alloc((size_t)n * 4 * 4);
  int*   gcnt   = (int*)alloc(256 * 4);
  int*   gcur   = (int*)alloc(256 * 4);
  int*   bst    = (int*)alloc(256 * 4);
  int*   offs   = (int*)alloc((size_t)n * 4);
  int*   cnts   = (int*)alloc((size_t)n * 4);
  unsigned int* tmp = (unsigned int*)alloc((size_t)E * 4);
  int*   csr    = (int*)alloc((size_t)E * 4);

  hipMemsetAsync(gcnt, 0, 256 * 4, stream);

  dim3 blk(256);
  const int NB = (n + 255) / 256;                 // node buckets (196)
  const int EB = (E + 256 * BIN_VPT - 1) / (256 * BIN_VPT);  // edge blocks
  k_mkfrag<<<8, blk, 0, stream>>>(W, wf);
  k_mkfrag<<<8, blk, 0, stream>>>(ow, owf);
  const int strips = (n + 15) / 16;
  k_gemm1<<<(strips + 3) / 4, blk, 0, stream>>>(x, wf, attn, Wxb, s_i, s_j, n);
  k_bcnt<<<EB, blk, 0, stream>>>(edges + E, gcnt, E);
  k_bscan<<<1, blk, 0, stream>>>(gcnt, gcur, bst);
  k_bin1<<<EB, blk, 0, stream>>>(edges, gcur, tmp, E);
  k_bin2<<<NB, blk, 0, stream>>>(tmp, bst, gcnt, csr, offs, cnts, n);
  k_agg<<<(n + AGG_WPB - 1) / AGG_WPB, blk, 0, stream>>>(Wxb, s_i, s_j, offs, cnts, csr, agb, n);
  k_gemm2<<<(strips + 3) / 4, blk, 0, stream>>>(agb, owf, ob, out, n);
}

// Round 5
// 106.677 us; speedup vs baseline: 4.0056x; 1.1436x over previous
//
#include <hip/hip_runtime.h>
#include <math.h>

// GAT layer: N=50000 nodes, E=800000 edges, D_IN=D_OUT=128, H=4, D_H=32
//
// 6-dispatch pipeline:
//   k_setup  : pack W / out_w into bf16 MFMA B-fragments + zero gcnt/gcur
//   k_gemm1b : Wx(bf16) = x @ W via MFMA + fused attention scores s_i/s_j;
//              trailing blocks do the dst-bucket histogram (bucket = dst>>8)
//   k_bin1   : block-local counting sort -> bucket-contiguous tmp (u32-packed
//              edges); bucket bases re-derived locally from gcnt (LDS scan)
//   k_bin2   : one block per bucket: node counts + scan (emits offs/cnts) +
//              placement — all scatter block-private
//   k_agg    : per-node pull softmax+aggregate (single pass, no max subtract;
//              |e| small so exp(e) is safe and ratios are identical), 8-way
//              unrolled row gather -> agg bf16
//   k_gemm2  : out = elu(agg @ out_w + out_b) via MFMA, f32 out

typedef __attribute__((ext_vector_type(8))) short short8;
typedef __attribute__((ext_vector_type(4))) float f32x4;

#define BIN_VPT 16          // edges per thread; 4096 edges per 256-thread block

__device__ __forceinline__ float lrelu(float v) { return v >= 0.f ? v : 0.2f * v; }

__device__ __forceinline__ unsigned short f2bf(float f) {  // RNE f32 -> bf16
  unsigned int u = __float_as_uint(f);
  u += 0x7FFFu + ((u >> 16) & 1u);
  return (unsigned short)(u >> 16);
}
__device__ __forceinline__ float bflo(unsigned int w) { return __uint_as_float(w << 16); }
__device__ __forceinline__ float bfhi(unsigned int w) { return __uint_as_float(w & 0xFFFF0000u); }

// 256-thread exclusive scan helper (value v per thread -> returns excl; ws[4] LDS)
__device__ __forceinline__ int blk_excl_scan(int v, int* ws) {
  const int t = threadIdx.x, lane = t & 63, wv = t >> 6;
  int incl = v;
#pragma unroll
  for (int m = 1; m < 64; m <<= 1) {
    int x = __shfl_up(incl, m, 64);
    if (lane >= m) incl += x;
  }
  if (lane == 63) ws[wv] = incl;
  __syncthreads();
  int woff = 0;
  for (int p = 0; p < wv; ++p) woff += ws[p];
  return woff + incl - v;
}

// ---------------------------------------------------------------- setup
// blocks 0..7: W fragments; 8..15: out_w fragments; blocks 0/1 also zero
// gcnt/gcur. F[((ks*8+nt)*64+lane)*8+j] = bf16(M[ks*32+(lane>>4)*8+j][nt*16+(lane&15)])
__global__ void k_setup(const float* __restrict__ W, const float* __restrict__ ow,
                        unsigned short* __restrict__ wf, unsigned short* __restrict__ owf,
                        int* __restrict__ gcnt, int* __restrict__ gcur) {
  const int t = blockIdx.x * 256 + threadIdx.x;
  if (blockIdx.x == 0) gcnt[threadIdx.x] = 0;
  if (blockIdx.x == 1) gcur[threadIdx.x] = 0;
  const int which = t >> 11;           // 0: W, 1: out_w
  const int tt = t & 2047;
  const float* M = which ? ow : W;
  unsigned short* F = which ? owf : wf;
  const int lane = tt & 63;
  const int nt = (tt >> 6) & 7;
  const int ks = tt >> 9;
  const int k0 = ks * 32 + (lane >> 4) * 8;
  const int col = nt * 16 + (lane & 15);
  short8 v;
#pragma unroll
  for (int j = 0; j < 8; ++j) v[j] = (short)f2bf(M[(k0 + j) * 128 + col]);
  *(short8*)(F + (size_t)tt * 8) = v;
}

// ---------------------------------------------------------------- GEMM1 + hist
__global__ void k_gemm1b(const float* __restrict__ x, const unsigned short* __restrict__ wf,
                         const float* __restrict__ attn, unsigned int* __restrict__ Wxb,
                         float* __restrict__ s_i, float* __restrict__ s_j, int n,
                         const int* __restrict__ dst, int* __restrict__ gcnt, int E,
                         int gemmBlocks) {
  __shared__ int lc[256];
  if (blockIdx.x >= gemmBlocks) {  // ---- histogram part
    const int bb = blockIdx.x - gemmBlocks;
    lc[threadIdx.x] = 0;
    __syncthreads();
    const int base = bb * (256 * BIN_VPT);
#pragma unroll
    for (int j = 0; j < BIN_VPT; ++j) {
      int e = base + j * 256 + threadIdx.x;
      if (e < E) atomicAdd(&lc[((unsigned int)dst[e]) >> 8], 1);
    }
    __syncthreads();
    int c = lc[threadIdx.x];
    if (c) atomicAdd(&gcnt[threadIdx.x], c);
    return;
  }

  // ---- GEMM part: one wave = 16-row strip, acc[nt] covers cols nt*16..+15
  const int lane = threadIdx.x & 63;
  const int gw = blockIdx.x * (blockDim.x >> 6) + (threadIdx.x >> 6);
  const int r0 = gw * 16;
  if (r0 >= n) return;
  const int g = lane >> 4, c = lane & 15;

  f32x4 acc[8];
#pragma unroll
  for (int nt = 0; nt < 8; ++nt) acc[nt] = (f32x4){0.f, 0.f, 0.f, 0.f};

  const int arow = min(r0 + c, n - 1);
#pragma unroll
  for (int ks = 0; ks < 4; ++ks) {
    const float* xr = x + (size_t)arow * 128 + ks * 32 + g * 8;
    float4 v0 = *(const float4*)xr;
    float4 v1 = *(const float4*)(xr + 4);
    short8 af;
    af[0] = (short)f2bf(v0.x); af[1] = (short)f2bf(v0.y);
    af[2] = (short)f2bf(v0.z); af[3] = (short)f2bf(v0.w);
    af[4] = (short)f2bf(v1.x); af[5] = (short)f2bf(v1.y);
    af[6] = (short)f2bf(v1.z); af[7] = (short)f2bf(v1.w);
#pragma unroll
    for (int nt = 0; nt < 8; ++nt) {
      short8 bf = *(const short8*)(wf + ((size_t)(ks * 8 + nt) * 64 + lane) * 8);
      acc[nt] = __builtin_amdgcn_mfma_f32_16x16x32_bf16(af, bf, acc[nt], 0, 0, 0);
    }
  }

  const int odd = c & 1;
#pragma unroll
  for (int r = 0; r < 4; ++r) {
    const int row = r0 + g * 4 + r;
    if (row >= n) continue;
    unsigned int* dp = Wxb + (size_t)row * 64;
#pragma unroll
    for (int ntp = 0; ntp < 4; ++ntp) {
      float ve = acc[ntp][r], vo = acc[ntp + 4][r];
      float vex = __shfl_xor(ve, 1, 64);
      float vox = __shfl_xor(vo, 1, 64);
      unsigned int lo = odd ? f2bf(vox) : f2bf(ve);
      unsigned int hi = odd ? f2bf(vo) : f2bf(vex);
      const int nt = odd ? ntp + 4 : ntp;
      dp[nt * 8 + (c >> 1)] = lo | (hi << 16);
    }
  }

  float aiv[8], ajv[8];
#pragma unroll
  for (int nt = 0; nt < 8; ++nt) {
    const int hh = nt >> 1, ch = (nt & 1) * 16 + c;
    aiv[nt] = attn[hh * 64 + ch];
    ajv[nt] = attn[hh * 64 + 32 + ch];
  }
#pragma unroll
  for (int r = 0; r < 4; ++r) {
    float pih[4], pjh[4];
#pragma unroll
    for (int h = 0; h < 4; ++h) {
      pih[h] = acc[2 * h][r] * aiv[2 * h] + acc[2 * h + 1][r] * aiv[2 * h + 1];
      pjh[h] = acc[2 * h][r] * ajv[2 * h] + acc[2 * h + 1][r] * ajv[2 * h + 1];
    }
#pragma unroll
    for (int m = 1; m < 16; m <<= 1) {
#pragma unroll
      for (int h = 0; h < 4; ++h) {
        pih[h] += __shfl_xor(pih[h], m, 64);
        pjh[h] += __shfl_xor(pjh[h], m, 64);
      }
    }
    const int row = r0 + g * 4 + r;
    if (c == 0 && row < n) {
#pragma unroll
      for (int h = 0; h < 4; ++h) {
        s_i[(size_t)row * 4 + h] = pih[h];
        s_j[(size_t)row * 4 + h] = pjh[h];
      }
    }
  }
}

// ---------------------------------------------------------------- bin1
// block-local counting sort into bucket-contiguous tmp (packed src | dst<<16);
// bucket bases derived locally from gcnt; gcur is a zero-based relative cursor.
__global__ void k_bin1(const int* __restrict__ edges, const int* __restrict__ gcnt,
                       int* __restrict__ gcur, unsigned int* __restrict__ tmp, int E) {
  __shared__ int ws[4];
  __shared__ int bst_s[256];
  __shared__ int lcnt[256];
  __shared__ int lbase[256];
  const int t = threadIdx.x;
  const int excl = blk_excl_scan(gcnt[t], ws);
  bst_s[t] = excl;
  lcnt[t] = 0;
  __syncthreads();
  const int base = blockIdx.x * (256 * BIN_VPT);
  unsigned int pv[BIN_VPT];
  int rk[BIN_VPT];
#pragma unroll
  for (int j = 0; j < BIN_VPT; ++j) {
    int e = base + j * 256 + t;
    if (e < E) {
      unsigned int s = (unsigned int)edges[e];
      unsigned int d = (unsigned int)edges[E + e];
      pv[j] = s | (d << 16);
      rk[j] = atomicAdd(&lcnt[d >> 8], 1);
    } else {
      pv[j] = 0u;
      rk[j] = -1;
    }
  }
  __syncthreads();
  const int c = lcnt[t];
  lbase[t] = bst_s[t] + (c ? atomicAdd(&gcur[t], c) : 0);
  __syncthreads();
#pragma unroll
  for (int j = 0; j < BIN_VPT; ++j) {
    if (rk[j] >= 0) {
      const int b = pv[j] >> 24;  // dst >> 8
      tmp[lbase[b] + rk[j]] = pv[j];
    }
  }
}

// ---------------------------------------------------------------- bin2
// one block per bucket: node counts -> scan (offs/cnts) -> placement
__global__ void k_bin2(const unsigned int* __restrict__ tmp, const int* __restrict__ gcnt,
                       int* __restrict__ csr, int* __restrict__ offs,
                       int* __restrict__ cnts, int n) {
  __shared__ int ws[4];
  __shared__ int bst_s[256];
  __shared__ int nc[256];
  const int b = blockIdx.x;
  const int t = threadIdx.x;
  bst_s[t] = blk_excl_scan(gcnt[t], ws);
  nc[t] = 0;
  __syncthreads();
  const int base = bst_s[b], cnt = gcnt[b];
  for (int i = t; i < cnt; i += 256)
    atomicAdd(&nc[(tmp[base + i] >> 16) & 255], 1);
  __syncthreads();
  const int node = b * 256 + t;
  const int c = nc[t];
  if (node < n) cnts[node] = c;
  __syncthreads();           // blk_excl_scan reuses ws; ensure count phase done
  const int excl = blk_excl_scan(c, ws);
  if (node < n) offs[node] = base + excl;
  __syncthreads();           // everyone done reading nc from count phase
  nc[t] = excl;              // becomes local cursor
  __syncthreads();
  for (int i = t; i < cnt; i += 256) {
    unsigned int v = tmp[base + i];
    int pos = atomicAdd(&nc[(v >> 16) & 255], 1);
    csr[base + pos] = (int)(v & 0xFFFFu);
  }
}

// ---------------------------------------------------------------- aggregate
#define AGG_WPB 4
__global__ void k_agg(const unsigned int* __restrict__ Wxb, const float* __restrict__ s_i,
                      const float* __restrict__ s_j, const int* __restrict__ offs,
                      const int* __restrict__ cnts, const int* __restrict__ csr_src,
                      unsigned int* __restrict__ aggb, int n) {
  __shared__ int   lsrc[AGG_WPB][64];
  __shared__ float lp[AGG_WPB][64][4];
  const int lane = threadIdx.x & 63;
  const int wv = threadIdx.x >> 6;
  const int nd = blockIdx.x * AGG_WPB + wv;
  if (nd >= n) return;
  const int base = offs[nd];
  const int deg = cnts[nd];
  const float4 sj = *(const float4*)(s_j + (size_t)nd * 4);
  const int h = lane >> 4;

  float4 smp = make_float4(0.f, 0.f, 0.f, 0.f);
  float2 acc = make_float2(0.f, 0.f);
  for (int c0 = 0; c0 < deg; c0 += 64) {
    const int m = min(64, deg - c0);
    if (lane < m) {
      int src = csr_src[base + c0 + lane];
      float4 si = *(const float4*)(s_i + (size_t)src * 4);
      float4 p;
      p.x = __expf(lrelu(si.x + sj.x));
      p.y = __expf(lrelu(si.y + sj.y));
      p.z = __expf(lrelu(si.z + sj.z));
      p.w = __expf(lrelu(si.w + sj.w));
      smp.x += p.x; smp.y += p.y; smp.z += p.z; smp.w += p.w;
      lsrc[wv][lane] = src;
      *(float4*)&lp[wv][lane][0] = p;
    }
    asm volatile("s_waitcnt lgkmcnt(0)" ::: "memory");  // same-wave LDS RAW
    int k = 0;
    for (; k + 8 <= m; k += 8) {  // 8 independent 256B row loads in flight
      int s0 = lsrc[wv][k + 0], s1 = lsrc[wv][k + 1];
      int s2 = lsrc[wv][k + 2], s3 = lsrc[wv][k + 3];
      int s4 = lsrc[wv][k + 4], s5 = lsrc[wv][k + 5];
      int s6 = lsrc[wv][k + 6], s7 = lsrc[wv][k + 7];
      float p0 = lp[wv][k + 0][h], p1 = lp[wv][k + 1][h];
      float p2 = lp[wv][k + 2][h], p3 = lp[wv][k + 3][h];
      float p4 = lp[wv][k + 4][h], p5 = lp[wv][k + 5][h];
      float p6 = lp[wv][k + 6][h], p7 = lp[wv][k + 7][h];
      unsigned int w0 = Wxb[(size_t)s0 * 64 + lane];
      unsigned int w1 = Wxb[(size_t)s1 * 64 + lane];
      unsigned int w2 = Wxb[(size_t)s2 * 64 + lane];
      unsigned int w3 = Wxb[(size_t)s3 * 64 + lane];
      unsigned int w4 = Wxb[(size_t)s4 * 64 + lane];
      unsigned int w5 = Wxb[(size_t)s5 * 64 + lane];
      unsigned int w6 = Wxb[(size_t)s6 * 64 + lane];
      unsigned int w7 = Wxb[(size_t)s7 * 64 + lane];
      acc.x += p0 * bflo(w0); acc.y += p0 * bfhi(w0);
      acc.x += p1 * bflo(w1); acc.y += p1 * bfhi(w1);
      acc.x += p2 * bflo(w2); acc.y += p2 * bfhi(w2);
      acc.x += p3 * bflo(w3); acc.y += p3 * bfhi(w3);
      acc.x += p4 * bflo(w4); acc.y += p4 * bfhi(w4);
      acc.x += p5 * bflo(w5); acc.y += p5 * bfhi(w5);
      acc.x += p6 * bflo(w6); acc.y += p6 * bfhi(w6);
      acc.x += p7 * bflo(w7); acc.y += p7 * bfhi(w7);
    }
    for (; k + 4 <= m; k += 4) {
      int s0 = lsrc[wv][k + 0], s1 = lsrc[wv][k + 1];
      int s2 = lsrc[wv][k + 2], s3 = lsrc[wv][k + 3];
      float p0 = lp[wv][k + 0][h], p1 = lp[wv][k + 1][h];
      float p2 = lp[wv][k + 2][h], p3 = lp[wv][k + 3][h];
      unsigned int w0 = Wxb[(size_t)s0 * 64 + lane];
      unsigned int w1 = Wxb[(size_t)s1 * 64 + lane];
      unsigned int w2 = Wxb[(size_t)s2 * 64 + lane];
      unsigned int w3 = Wxb[(size_t)s3 * 64 + lane];
      acc.x += p0 * bflo(w0); acc.y += p0 * bfhi(w0);
      acc.x += p1 * bflo(w1); acc.y += p1 * bfhi(w1);
      acc.x += p2 * bflo(w2); acc.y += p2 * bfhi(w2);
      acc.x += p3 * bflo(w3); acc.y += p3 * bfhi(w3);
    }
    for (; k < m; ++k) {
      int s = lsrc[wv][k];
      float pv = lp[wv][k][h];
      unsigned int w = Wxb[(size_t)s * 64 + lane];
      acc.x += pv * bflo(w); acc.y += pv * bfhi(w);
    }
  }
#pragma unroll
  for (int m = 1; m < 64; m <<= 1) {
    smp.x += __shfl_xor(smp.x, m, 64);
    smp.y += __shfl_xor(smp.y, m, 64);
    smp.z += __shfl_xor(smp.z, m, 64);
    smp.w += __shfl_xor(smp.w, m, 64);
  }
  float sh = (h & 2) ? ((h & 1) ? smp.w : smp.z) : ((h & 1) ? smp.y : smp.x);
  const float inv = 1.f / (sh + 1e-16f);
  unsigned int lo = f2bf(acc.x * inv), hi = f2bf(acc.y * inv);
  aggb[(size_t)nd * 64 + lane] = lo | (hi << 16);
}

// ---------------------------------------------------------------- GEMM 2
__global__ void k_gemm2(const unsigned int* __restrict__ aggb,
                        const unsigned short* __restrict__ owf,
                        const float* __restrict__ ob, float* __restrict__ out, int n) {
  const int lane = threadIdx.x & 63;
  const int gw = blockIdx.x * (blockDim.x >> 6) + (threadIdx.x >> 6);
  const int r0 = gw * 16;
  if (r0 >= n) return;
  const int g = lane >> 4, c = lane & 15;

  f32x4 acc[8];
#pragma unroll
  for (int nt = 0; nt < 8; ++nt) acc[nt] = (f32x4){0.f, 0.f, 0.f, 0.f};

  const int arow = min(r0 + c, n - 1);
#pragma unroll
  for (int ks = 0; ks < 4; ++ks) {
    const unsigned int* ar = aggb + (size_t)arow * 64 + ks * 16 + g * 4;
    uint4 av = *(const uint4*)ar;
    short8 af;
    af[0] = (short)(av.x & 0xFFFF); af[1] = (short)(av.x >> 16);
    af[2] = (short)(av.y & 0xFFFF); af[3] = (short)(av.y >> 16);
    af[4] = (short)(av.z & 0xFFFF); af[5] = (short)(av.z >> 16);
    af[6] = (short)(av.w & 0xFFFF); af[7] = (short)(av.w >> 16);
#pragma unroll
    for (int nt = 0; nt < 8; ++nt) {
      short8 bf = *(const short8*)(owf + ((size_t)(ks * 8 + nt) * 64 + lane) * 8);
      acc[nt] = __builtin_amdgcn_mfma_f32_16x16x32_bf16(af, bf, acc[nt], 0, 0, 0);
    }
  }

#pragma unroll
  for (int r = 0; r < 4; ++r) {
    const int row = r0 + g * 4 + r;
    if (row >= n) continue;
    float* dst = out + (size_t)row * 128;
#pragma unroll
    for (int nt = 0; nt < 8; ++nt) {
      float v = acc[nt][r] + ob[nt * 16 + c];
      v = v > 0.f ? v : expm1f(v);
      dst[nt * 16 + c] = v;
    }
  }
}

// ---------------------------------------------------------------- launch
extern "C" void kernel_launch(void* const* d_in, const int* in_sizes, int n_in,
                              void* d_out, int out_size, void* d_ws, size_t ws_size,
                              hipStream_t stream) {
  const float* x    = (const float*)d_in[0];
  const int*   edges = (const int*)d_in[1];   // [2,E] (src row then dst row)
  const float* W    = (const float*)d_in[2];
  const float* attn = (const float*)d_in[3];
  const float* ow   = (const float*)d_in[4];
  const float* ob   = (const float*)d_in[5];
  const int n = in_sizes[0] / 128;            // 50000 (< 65536: u32 edge pack)
  const int E = in_sizes[1] / 2;
  float* out = (float*)d_out;

  char* wp = (char*)d_ws;
  auto alloc = [&](size_t bytes) {
    char* p = wp;
    wp += (bytes + 255) & ~(size_t)255;
    return p;
  };
  unsigned short* wf  = (unsigned short*)alloc(2048 * 8 * 2);
  unsigned short* owf = (unsigned short*)alloc(2048 * 8 * 2);
  unsigned int*   Wxb = (unsigned int*)alloc((size_t)n * 64 * 4);
  unsigned int*   agb = (unsigned int*)alloc((size_t)n * 64 * 4);
  float* s_i    = (float*)alloc((size_t)n * 4 * 4);
  float* s_j    = (float*)alloc((size_t)n * 4 * 4);
  int*   gcnt   = (int*)alloc(256 * 4);
  int*   gcur   = (int*)alloc(256 * 4);
  int*   offs   = (int*)alloc((size_t)n * 4);
  int*   cnts   = (int*)alloc((size_t)n * 4);
  unsigned int* tmp = (unsigned int*)alloc((size_t)E * 4);
  int*   csr    = (int*)alloc((size_t)E * 4);

  dim3 blk(256);
  const int NB = (n + 255) / 256;                            // node buckets (196)
  const int EB = (E + 256 * BIN_VPT - 1) / (256 * BIN_VPT);  // edge blocks (196)
  const int strips = (n + 15) / 16;
  const int gemmBlocks = (strips + 3) / 4;

  k_setup<<<16, blk, 0, stream>>>(W, ow, wf, owf, gcnt, gcur);
  k_gemm1b<<<gemmBlocks + EB, blk, 0, stream>>>(x, wf, attn, Wxb, s_i, s_j, n,
                                                edges + E, gcnt, E, gemmBlocks);
  k_bin1<<<EB, blk, 0, stream>>>(edges, gcnt, gcur, tmp, E);
  k_bin2<<<NB, blk, 0, stream>>>(tmp, gcnt, csr, offs, cnts, n);
  k_agg<<<(n + AGG_WPB - 1) / AGG_WPB, blk, 0, stream>>>(Wxb, s_i, s_j, offs, cnts, csr, agb, n);
  k_gemm2<<<gemmBlocks, blk, 0, stream>>>(agb, owf, ob, out, n);
}

// Round 6
// 104.054 us; speedup vs baseline: 4.1065x; 1.0252x over previous
//
#include <hip/hip_runtime.h>
#include <math.h>

// GAT layer: N=50000 nodes, E=800000 edges, D_IN=D_OUT=128, H=4, D_H=32
//
// 5-dispatch pipeline:
//   k_setup  : pack W / out_w into bf16 MFMA B-fragments + zero gcnt/gcur
//   k_gemm1b : Wx(bf16) = x @ W via MFMA + fused attention scores s_i/s_j;
//              trailing blocks do the dst-bucket histogram (bucket = dst>>8)
//   k_bin1   : block-local counting sort -> bucket-contiguous tmp (u32-packed
//              edges); bucket bases re-derived locally from gcnt (LDS scan)
//   k_bin2   : one block per bucket: node counts + scan (emits offs/cnts) +
//              placement — all scatter block-private
//   k_aggm   : 16 waves/block; each wave: pull softmax+aggregate one node
//              (no max subtract; |e| small so exp(e) safe, ratios identical)
//              -> bf16 row into padded LDS tile; then waves 0..7 apply the
//              output GEMM (4 MFMAs each) + bias + ELU directly to d_out.

typedef __attribute__((ext_vector_type(8))) short short8;
typedef __attribute__((ext_vector_type(4))) float f32x4;

#define BIN_VPT 16          // edges per thread; 4096 edges per 256-thread block

__device__ __forceinline__ float lrelu(float v) { return v >= 0.f ? v : 0.2f * v; }

__device__ __forceinline__ unsigned short f2bf(float f) {  // RNE f32 -> bf16
  unsigned int u = __float_as_uint(f);
  u += 0x7FFFu + ((u >> 16) & 1u);
  return (unsigned short)(u >> 16);
}
// HW packed RNE convert: dst = bf16(lo) | bf16(hi)<<16   (gfx950 T12 recipe)
__device__ __forceinline__ unsigned int cvt_pk_bf16(float lo, float hi) {
  unsigned int r;
  asm("v_cvt_pk_bf16_f32 %0, %1, %2" : "=v"(r) : "v"(lo), "v"(hi));
  return r;
}
__device__ __forceinline__ float bflo(unsigned int w) { return __uint_as_float(w << 16); }
__device__ __forceinline__ float bfhi(unsigned int w) { return __uint_as_float(w & 0xFFFF0000u); }

// 256-thread exclusive scan helper (value v per thread -> returns excl; ws[4] LDS)
__device__ __forceinline__ int blk_excl_scan(int v, int* ws) {
  const int t = threadIdx.x, lane = t & 63, wv = t >> 6;
  int incl = v;
#pragma unroll
  for (int m = 1; m < 64; m <<= 1) {
    int x = __shfl_up(incl, m, 64);
    if (lane >= m) incl += x;
  }
  if (lane == 63) ws[wv] = incl;
  __syncthreads();
  int woff = 0;
  for (int p = 0; p < wv; ++p) woff += ws[p];
  return woff + incl - v;
}

// ---------------------------------------------------------------- setup
// blocks 0..7: W fragments; 8..15: out_w fragments; blocks 0/1 zero gcnt/gcur.
// F[((ks*8+nt)*64+lane)*8+j] = bf16(M[ks*32+(lane>>4)*8+j][nt*16+(lane&15)])
__global__ void k_setup(const float* __restrict__ W, const float* __restrict__ ow,
                        unsigned short* __restrict__ wf, unsigned short* __restrict__ owf,
                        int* __restrict__ gcnt, int* __restrict__ gcur) {
  const int t = blockIdx.x * 256 + threadIdx.x;
  if (blockIdx.x == 0) gcnt[threadIdx.x] = 0;
  if (blockIdx.x == 1) gcur[threadIdx.x] = 0;
  const int which = t >> 11;           // 0: W, 1: out_w
  const int tt = t & 2047;
  const float* M = which ? ow : W;
  unsigned short* F = which ? owf : wf;
  const int lane = tt & 63;
  const int nt = (tt >> 6) & 7;
  const int ks = tt >> 9;
  const int k0 = ks * 32 + (lane >> 4) * 8;
  const int col = nt * 16 + (lane & 15);
  short8 v;
#pragma unroll
  for (int j = 0; j < 8; ++j) v[j] = (short)f2bf(M[(k0 + j) * 128 + col]);
  *(short8*)(F + (size_t)tt * 8) = v;
}

// ---------------------------------------------------------------- GEMM1 + hist
__global__ void k_gemm1b(const float* __restrict__ x, const unsigned short* __restrict__ wf,
                         const float* __restrict__ attn, unsigned int* __restrict__ Wxb,
                         float* __restrict__ s_i, float* __restrict__ s_j, int n,
                         const int* __restrict__ dst, int* __restrict__ gcnt, int E,
                         int gemmBlocks) {
  __shared__ int lc[256];
  if (blockIdx.x >= gemmBlocks) {  // ---- histogram part
    const int bb = blockIdx.x - gemmBlocks;
    lc[threadIdx.x] = 0;
    __syncthreads();
    const int base = bb * (256 * BIN_VPT);
#pragma unroll
    for (int j = 0; j < BIN_VPT; ++j) {
      int e = base + j * 256 + threadIdx.x;
      if (e < E) atomicAdd(&lc[((unsigned int)dst[e]) >> 8], 1);
    }
    __syncthreads();
    int c = lc[threadIdx.x];
    if (c) atomicAdd(&gcnt[threadIdx.x], c);
    return;
  }

  // ---- GEMM part: one wave = 16-row strip, acc[nt] covers cols nt*16..+15
  const int lane = threadIdx.x & 63;
  const int gw = blockIdx.x * (blockDim.x >> 6) + (threadIdx.x >> 6);
  const int r0 = gw * 16;
  if (r0 >= n) return;
  const int g = lane >> 4, c = lane & 15;

  f32x4 acc[8];
#pragma unroll
  for (int nt = 0; nt < 8; ++nt) acc[nt] = (f32x4){0.f, 0.f, 0.f, 0.f};

  const int arow = min(r0 + c, n - 1);
#pragma unroll
  for (int ks = 0; ks < 4; ++ks) {
    const float* xr = x + (size_t)arow * 128 + ks * 32 + g * 8;
    float4 v0 = *(const float4*)xr;
    float4 v1 = *(const float4*)(xr + 4);
    uint4 au;
    au.x = cvt_pk_bf16(v0.x, v0.y);
    au.y = cvt_pk_bf16(v0.z, v0.w);
    au.z = cvt_pk_bf16(v1.x, v1.y);
    au.w = cvt_pk_bf16(v1.z, v1.w);
    short8 af = __builtin_bit_cast(short8, au);
#pragma unroll
    for (int nt = 0; nt < 8; ++nt) {
      short8 bf = *(const short8*)(wf + ((size_t)(ks * 8 + nt) * 64 + lane) * 8);
      acc[nt] = __builtin_amdgcn_mfma_f32_16x16x32_bf16(af, bf, acc[nt], 0, 0, 0);
    }
  }

  const int odd = c & 1;
#pragma unroll
  for (int r = 0; r < 4; ++r) {
    const int row = r0 + g * 4 + r;
    if (row >= n) continue;
    unsigned int* dp = Wxb + (size_t)row * 64;
#pragma unroll
    for (int ntp = 0; ntp < 4; ++ntp) {
      float ve = acc[ntp][r], vo = acc[ntp + 4][r];
      float vex = __shfl_xor(ve, 1, 64);
      float vox = __shfl_xor(vo, 1, 64);
      const int nt = odd ? ntp + 4 : ntp;
      dp[nt * 8 + (c >> 1)] = cvt_pk_bf16(odd ? vox : ve, odd ? vo : vex);
    }
  }

  float aiv[8], ajv[8];
#pragma unroll
  for (int nt = 0; nt < 8; ++nt) {
    const int hh = nt >> 1, ch = (nt & 1) * 16 + c;
    aiv[nt] = attn[hh * 64 + ch];
    ajv[nt] = attn[hh * 64 + 32 + ch];
  }
#pragma unroll
  for (int r = 0; r < 4; ++r) {
    float pih[4], pjh[4];
#pragma unroll
    for (int h = 0; h < 4; ++h) {
      pih[h] = acc[2 * h][r] * aiv[2 * h] + acc[2 * h + 1][r] * aiv[2 * h + 1];
      pjh[h] = acc[2 * h][r] * ajv[2 * h] + acc[2 * h + 1][r] * ajv[2 * h + 1];
    }
#pragma unroll
    for (int m = 1; m < 16; m <<= 1) {
#pragma unroll
      for (int h = 0; h < 4; ++h) {
        pih[h] += __shfl_xor(pih[h], m, 64);
        pjh[h] += __shfl_xor(pjh[h], m, 64);
      }
    }
    const int row = r0 + g * 4 + r;
    if (c == 0 && row < n) {
#pragma unroll
      for (int h = 0; h < 4; ++h) {
        s_i[(size_t)row * 4 + h] = pih[h];
        s_j[(size_t)row * 4 + h] = pjh[h];
      }
    }
  }
}

// ---------------------------------------------------------------- bin1
// block-local counting sort into bucket-contiguous tmp (packed src | dst<<16);
// bucket bases derived locally from gcnt; gcur is a zero-based relative cursor.
__global__ void k_bin1(const int* __restrict__ edges, const int* __restrict__ gcnt,
                       int* __restrict__ gcur, unsigned int* __restrict__ tmp, int E) {
  __shared__ int ws[4];
  __shared__ int bst_s[256];
  __shared__ int lcnt[256];
  __shared__ int lbase[256];
  const int t = threadIdx.x;
  const int excl = blk_excl_scan(gcnt[t], ws);
  bst_s[t] = excl;
  lcnt[t] = 0;
  __syncthreads();
  const int base = blockIdx.x * (256 * BIN_VPT);
  unsigned int pv[BIN_VPT];
  int rk[BIN_VPT];
#pragma unroll
  for (int j = 0; j < BIN_VPT; ++j) {
    int e = base + j * 256 + t;
    if (e < E) {
      unsigned int s = (unsigned int)edges[e];
      unsigned int d = (unsigned int)edges[E + e];
      pv[j] = s | (d << 16);
      rk[j] = atomicAdd(&lcnt[d >> 8], 1);
    } else {
      pv[j] = 0u;
      rk[j] = -1;
    }
  }
  __syncthreads();
  const int c = lcnt[t];
  lbase[t] = bst_s[t] + (c ? atomicAdd(&gcur[t], c) : 0);
  __syncthreads();
#pragma unroll
  for (int j = 0; j < BIN_VPT; ++j) {
    if (rk[j] >= 0) {
      const int b = pv[j] >> 24;  // dst >> 8
      tmp[lbase[b] + rk[j]] = pv[j];
    }
  }
}

// ---------------------------------------------------------------- bin2
// one block per bucket: node counts -> scan (offs/cnts) -> placement
__global__ void k_bin2(const unsigned int* __restrict__ tmp, const int* __restrict__ gcnt,
                       int* __restrict__ csr, int* __restrict__ offs,
                       int* __restrict__ cnts, int n) {
  __shared__ int ws[4];
  __shared__ int bst_s[256];
  __shared__ int nc[256];
  const int b = blockIdx.x;
  const int t = threadIdx.x;
  bst_s[t] = blk_excl_scan(gcnt[t], ws);
  nc[t] = 0;
  __syncthreads();
  const int base = bst_s[b], cnt = gcnt[b];
  for (int i = t; i < cnt; i += 256)
    atomicAdd(&nc[(tmp[base + i] >> 16) & 255], 1);
  __syncthreads();
  const int node = b * 256 + t;
  const int c = nc[t];
  if (node < n) cnts[node] = c;
  __syncthreads();           // blk_excl_scan reuses ws; ensure count phase done
  const int excl = blk_excl_scan(c, ws);
  if (node < n) offs[node] = base + excl;
  __syncthreads();           // everyone done reading nc from count phase
  nc[t] = excl;              // becomes local cursor
  __syncthreads();
  for (int i = t; i < cnt; i += 256) {
    unsigned int v = tmp[base + i];
    int pos = atomicAdd(&nc[(v >> 16) & 255], 1);
    csr[base + pos] = (int)(v & 0xFFFFu);
  }
}

// ---------------------------------------------------------------- agg + GEMM2
// 16 waves/block, 1024 threads. Phase 1: wave wv aggregates node
// blockIdx*16+wv into a packed-bf16 row in the padded LDS tile (row stride 65
// u32 => 65 = 1 mod 32, conflict-free column reads). Phase 2: waves 0..7 each
// compute one 16-col tile of out = elu(aggTile @ out_w + out_b) via 4 MFMAs.
__global__ void k_aggm(const unsigned int* __restrict__ Wxb, const float* __restrict__ s_i,
                       const float* __restrict__ s_j, const int* __restrict__ offs,
                       const int* __restrict__ cnts, const int* __restrict__ csr_src,
                       const unsigned short* __restrict__ owf, const float* __restrict__ ob,
                       float* __restrict__ out, int n) {
  __shared__ unsigned int aTile[16][65];
  __shared__ int   lsrc[16][64];
  __shared__ float lp[16][64][4];
  const int lane = threadIdx.x & 63;
  const int wv = threadIdx.x >> 6;
  const int nd0 = blockIdx.x * 16;
  const int nd = nd0 + wv;
  const int h = lane >> 4;

  int base = 0, deg = 0;
  float4 sj = make_float4(0.f, 0.f, 0.f, 0.f);
  if (nd < n) {
    base = offs[nd];
    deg = cnts[nd];
    sj = *(const float4*)(s_j + (size_t)nd * 4);
  }

  float4 smp = make_float4(0.f, 0.f, 0.f, 0.f);
  float2 acc = make_float2(0.f, 0.f);
  for (int c0 = 0; c0 < deg; c0 += 64) {
    const int m = min(64, deg - c0);
    if (lane < m) {
      int src = csr_src[base + c0 + lane];
      float4 si = *(const float4*)(s_i + (size_t)src * 4);
      float4 p;
      p.x = __expf(lrelu(si.x + sj.x));
      p.y = __expf(lrelu(si.y + sj.y));
      p.z = __expf(lrelu(si.z + sj.z));
      p.w = __expf(lrelu(si.w + sj.w));
      smp.x += p.x; smp.y += p.y; smp.z += p.z; smp.w += p.w;
      lsrc[wv][lane] = src;
      *(float4*)&lp[wv][lane][0] = p;
    }
    asm volatile("s_waitcnt lgkmcnt(0)" ::: "memory");  // same-wave LDS RAW
    int k = 0;
    for (; k + 8 <= m; k += 8) {  // 8 independent 256B row loads in flight
      int s0 = lsrc[wv][k + 0], s1 = lsrc[wv][k + 1];
      int s2 = lsrc[wv][k + 2], s3 = lsrc[wv][k + 3];
      int s4 = lsrc[wv][k + 4], s5 = lsrc[wv][k + 5];
      int s6 = lsrc[wv][k + 6], s7 = lsrc[wv][k + 7];
      float p0 = lp[wv][k + 0][h], p1 = lp[wv][k + 1][h];
      float p2 = lp[wv][k + 2][h], p3 = lp[wv][k + 3][h];
      float p4 = lp[wv][k + 4][h], p5 = lp[wv][k + 5][h];
      float p6 = lp[wv][k + 6][h], p7 = lp[wv][k + 7][h];
      unsigned int w0 = Wxb[(size_t)s0 * 64 + lane];
      unsigned int w1 = Wxb[(size_t)s1 * 64 + lane];
      unsigned int w2 = Wxb[(size_t)s2 * 64 + lane];
      unsigned int w3 = Wxb[(size_t)s3 * 64 + lane];
      unsigned int w4 = Wxb[(size_t)s4 * 64 + lane];
      unsigned int w5 = Wxb[(size_t)s5 * 64 + lane];
      unsigned int w6 = Wxb[(size_t)s6 * 64 + lane];
      unsigned int w7 = Wxb[(size_t)s7 * 64 + lane];
      acc.x += p0 * bflo(w0); acc.y += p0 * bfhi(w0);
      acc.x += p1 * bflo(w1); acc.y += p1 * bfhi(w1);
      acc.x += p2 * bflo(w2); acc.y += p2 * bfhi(w2);
      acc.x += p3 * bflo(w3); acc.y += p3 * bfhi(w3);
      acc.x += p4 * bflo(w4); acc.y += p4 * bfhi(w4);
      acc.x += p5 * bflo(w5); acc.y += p5 * bfhi(w5);
      acc.x += p6 * bflo(w6); acc.y += p6 * bfhi(w6);
      acc.x += p7 * bflo(w7); acc.y += p7 * bfhi(w7);
    }
    for (; k + 4 <= m; k += 4) {
      int s0 = lsrc[wv][k + 0], s1 = lsrc[wv][k + 1];
      int s2 = lsrc[wv][k + 2], s3 = lsrc[wv][k + 3];
      float p0 = lp[wv][k + 0][h], p1 = lp[wv][k + 1][h];
      float p2 = lp[wv][k + 2][h], p3 = lp[wv][k + 3][h];
      unsigned int w0 = Wxb[(size_t)s0 * 64 + lane];
      unsigned int w1 = Wxb[(size_t)s1 * 64 + lane];
      unsigned int w2 = Wxb[(size_t)s2 * 64 + lane];
      unsigned int w3 = Wxb[(size_t)s3 * 64 + lane];
      acc.x += p0 * bflo(w0); acc.y += p0 * bfhi(w0);
      acc.x += p1 * bflo(w1); acc.y += p1 * bfhi(w1);
      acc.x += p2 * bflo(w2); acc.y += p2 * bfhi(w2);
      acc.x += p3 * bflo(w3); acc.y += p3 * bfhi(w3);
    }
    for (; k < m; ++k) {
      int s = lsrc[wv][k];
      float pv = lp[wv][k][h];
      unsigned int w = Wxb[(size_t)s * 64 + lane];
      acc.x += pv * bflo(w); acc.y += pv * bfhi(w);
    }
  }
#pragma unroll
  for (int m = 1; m < 64; m <<= 1) {
    smp.x += __shfl_xor(smp.x, m, 64);
    smp.y += __shfl_xor(smp.y, m, 64);
    smp.z += __shfl_xor(smp.z, m, 64);
    smp.w += __shfl_xor(smp.w, m, 64);
  }
  float sh = (h & 2) ? ((h & 1) ? smp.w : smp.z) : ((h & 1) ? smp.y : smp.x);
  const float inv = 1.f / (sh + 1e-16f);
  aTile[wv][lane] = cvt_pk_bf16(acc.x * inv, acc.y * inv);
  __syncthreads();

  // ---- phase 2: out-GEMM on the 16-row tile (waves 0..7, one col-tile each)
  if (wv < 8) {
    const int g = lane >> 4, c = lane & 15;
    const int nt = wv;
    f32x4 o = (f32x4){0.f, 0.f, 0.f, 0.f};
#pragma unroll
    for (int ks = 0; ks < 4; ++ks) {
      uint4 au = *(const uint4*)&aTile[c][ks * 16 + g * 4];  // A row = lane&15
      short8 af = __builtin_bit_cast(short8, au);
      short8 bf = *(const short8*)(owf + ((size_t)(ks * 8 + nt) * 64 + lane) * 8);
      o = __builtin_amdgcn_mfma_f32_16x16x32_bf16(af, bf, o, 0, 0, 0);
    }
#pragma unroll
    for (int r = 0; r < 4; ++r) {
      const int row = nd0 + g * 4 + r;   // D row = (lane>>4)*4 + r
      if (row < n) {
        float v = o[r] + ob[nt * 16 + c];
        v = v > 0.f ? v : expm1f(v);
        out[(size_t)row * 128 + nt * 16 + c] = v;
      }
    }
  }
}

// ---------------------------------------------------------------- launch
extern "C" void kernel_launch(void* const* d_in, const int* in_sizes, int n_in,
                              void* d_out, int out_size, void* d_ws, size_t ws_size,
                              hipStream_t stream) {
  const float* x    = (const float*)d_in[0];
  const int*   edges = (const int*)d_in[1];   // [2,E] (src row then dst row)
  const float* W    = (const float*)d_in[2];
  const float* attn = (const float*)d_in[3];
  const float* ow   = (const float*)d_in[4];
  const float* ob   = (const float*)d_in[5];
  const int n = in_sizes[0] / 128;            // 50000 (< 65536: u32 edge pack)
  const int E = in_sizes[1] / 2;
  float* out = (float*)d_out;

  char* wp = (char*)d_ws;
  auto alloc = [&](size_t bytes) {
    char* p = wp;
    wp += (bytes + 255) & ~(size_t)255;
    return p;
  };
  unsigned short* wf  = (unsigned short*)alloc(2048 * 8 * 2);
  unsigned short* owf = (unsigned short*)alloc(2048 * 8 * 2);
  unsigned int*   Wxb = (unsigned int*)alloc((size_t)n * 64 * 4);
  float* s_i    = (float*)alloc((size_t)n * 4 * 4);
  float* s_j    = (float*)alloc((size_t)n * 4 * 4);
  int*   gcnt   = (int*)alloc(256 * 4);
  int*   gcur   = (int*)alloc(256 * 4);
  int*   offs   = (int*)alloc((size_t)n * 4);
  int*   cnts   = (int*)alloc((size_t)n * 4);
  unsigned int* tmp = (unsigned int*)alloc((size_t)E * 4);
  int*   csr    = (int*)alloc((size_t)E * 4);

  dim3 blk(256);
  const int NB = (n + 255) / 256;                            // node buckets (196)
  const int EB = (E + 256 * BIN_VPT - 1) / (256 * BIN_VPT);  // edge blocks (196)
  const int strips = (n + 15) / 16;
  const int gemmBlocks = (strips + 3) / 4;

  k_setup<<<16, blk, 0, stream>>>(W, ow, wf, owf, gcnt, gcur);
  k_gemm1b<<<gemmBlocks + EB, blk, 0, stream>>>(x, wf, attn, Wxb, s_i, s_j, n,
                                                edges + E, gcnt, E, gemmBlocks);
  k_bin1<<<EB, blk, 0, stream>>>(edges, gcnt, gcur, tmp, E);
  k_bin2<<<NB, blk, 0, stream>>>(tmp, gcnt, csr, offs, cnts, n);
  k_aggm<<<(n + 15) / 16, dim3(1024), 0, stream>>>(Wxb, s_i, s_j, offs, cnts, csr,
                                                   owf, ob, out, n);
}

// Round 7
// 96.156 us; speedup vs baseline: 4.4438x; 1.0821x over previous
//
#include <hip/hip_runtime.h>
#include <math.h>

// GAT layer: N=50000 nodes, E=800000 edges, D_IN=D_OUT=128, H=4, D_H=32
//
// 5-dispatch pipeline:
//   k_setup  : pack W / out_w into bf16 MFMA B-fragments + zero gcnt/gcur
//   k_gemm1b : Wx(bf16) = x @ W via MFMA + fused attention scores s_i/s_j;
//              trailing blocks do the dst-bucket histogram (bucket = dst>>8)
//   k_bin1   : block-local counting sort -> bucket-contiguous tmp
//   k_bin2   : one block per bucket: node counts + scan (emits offs/cnts) +
//              placement — all scatter block-private
//   k_aggm   : 4 waves/block, 4 consecutive nodes per wave. Wave stages 64
//              edges at a time across ALL its nodes (full-wave staging; edge's
//              node derived from position vs degree boundaries), then a
//              boundary-walking sequential gather accumulates and finalizes
//              each node's bf16 row into the LDS tile. Per-head exp-sum falls
//              out of the same loop (no shuffle reduction). Phase 2: all 4
//              waves run the output GEMM (2 col-tiles each) + bias + ELU.

typedef __attribute__((ext_vector_type(8))) short short8;
typedef __attribute__((ext_vector_type(4))) float f32x4;

#define BIN_VPT 16          // edges per thread; 4096 edges per 256-thread block

__device__ __forceinline__ float lrelu(float v) { return v >= 0.f ? v : 0.2f * v; }

__device__ __forceinline__ unsigned short f2bf(float f) {  // RNE f32 -> bf16
  unsigned int u = __float_as_uint(f);
  u += 0x7FFFu + ((u >> 16) & 1u);
  return (unsigned short)(u >> 16);
}
// HW packed RNE convert: dst = bf16(lo) | bf16(hi)<<16
__device__ __forceinline__ unsigned int cvt_pk_bf16(float lo, float hi) {
  unsigned int r;
  asm("v_cvt_pk_bf16_f32 %0, %1, %2" : "=v"(r) : "v"(lo), "v"(hi));
  return r;
}
__device__ __forceinline__ float bflo(unsigned int w) { return __uint_as_float(w << 16); }
__device__ __forceinline__ float bfhi(unsigned int w) { return __uint_as_float(w & 0xFFFF0000u); }

// 256-thread exclusive scan helper (value v per thread -> returns excl; ws[4] LDS)
__device__ __forceinline__ int blk_excl_scan(int v, int* ws) {
  const int t = threadIdx.x, lane = t & 63, wv = t >> 6;
  int incl = v;
#pragma unroll
  for (int m = 1; m < 64; m <<= 1) {
    int x = __shfl_up(incl, m, 64);
    if (lane >= m) incl += x;
  }
  if (lane == 63) ws[wv] = incl;
  __syncthreads();
  int woff = 0;
  for (int p = 0; p < wv; ++p) woff += ws[p];
  return woff + incl - v;
}

// ---------------------------------------------------------------- setup
__global__ void k_setup(const float* __restrict__ W, const float* __restrict__ ow,
                        unsigned short* __restrict__ wf, unsigned short* __restrict__ owf,
                        int* __restrict__ gcnt, int* __restrict__ gcur) {
  const int t = blockIdx.x * 256 + threadIdx.x;
  if (blockIdx.x == 0) gcnt[threadIdx.x] = 0;
  if (blockIdx.x == 1) gcur[threadIdx.x] = 0;
  const int which = t >> 11;           // 0: W, 1: out_w
  const int tt = t & 2047;
  const float* M = which ? ow : W;
  unsigned short* F = which ? owf : wf;
  const int lane = tt & 63;
  const int nt = (tt >> 6) & 7;
  const int ks = tt >> 9;
  const int k0 = ks * 32 + (lane >> 4) * 8;
  const int col = nt * 16 + (lane & 15);
  short8 v;
#pragma unroll
  for (int j = 0; j < 8; ++j) v[j] = (short)f2bf(M[(k0 + j) * 128 + col]);
  *(short8*)(F + (size_t)tt * 8) = v;
}

// ---------------------------------------------------------------- GEMM1 + hist
__global__ void k_gemm1b(const float* __restrict__ x, const unsigned short* __restrict__ wf,
                         const float* __restrict__ attn, unsigned int* __restrict__ Wxb,
                         float* __restrict__ s_i, float* __restrict__ s_j, int n,
                         const int* __restrict__ dst, int* __restrict__ gcnt, int E,
                         int gemmBlocks) {
  __shared__ int lc[256];
  if (blockIdx.x >= gemmBlocks) {  // ---- histogram part
    const int bb = blockIdx.x - gemmBlocks;
    lc[threadIdx.x] = 0;
    __syncthreads();
    const int base = bb * (256 * BIN_VPT);
#pragma unroll
    for (int j = 0; j < BIN_VPT; ++j) {
      int e = base + j * 256 + threadIdx.x;
      if (e < E) atomicAdd(&lc[((unsigned int)dst[e]) >> 8], 1);
    }
    __syncthreads();
    int c = lc[threadIdx.x];
    if (c) atomicAdd(&gcnt[threadIdx.x], c);
    return;
  }

  // ---- GEMM part: one wave = 16-row strip, acc[nt] covers cols nt*16..+15
  const int lane = threadIdx.x & 63;
  const int gw = blockIdx.x * (blockDim.x >> 6) + (threadIdx.x >> 6);
  const int r0 = gw * 16;
  if (r0 >= n) return;
  const int g = lane >> 4, c = lane & 15;

  f32x4 acc[8];
#pragma unroll
  for (int nt = 0; nt < 8; ++nt) acc[nt] = (f32x4){0.f, 0.f, 0.f, 0.f};

  const int arow = min(r0 + c, n - 1);
#pragma unroll
  for (int ks = 0; ks < 4; ++ks) {
    const float* xr = x + (size_t)arow * 128 + ks * 32 + g * 8;
    float4 v0 = *(const float4*)xr;
    float4 v1 = *(const float4*)(xr + 4);
    uint4 au;
    au.x = cvt_pk_bf16(v0.x, v0.y);
    au.y = cvt_pk_bf16(v0.z, v0.w);
    au.z = cvt_pk_bf16(v1.x, v1.y);
    au.w = cvt_pk_bf16(v1.z, v1.w);
    short8 af = __builtin_bit_cast(short8, au);
#pragma unroll
    for (int nt = 0; nt < 8; ++nt) {
      short8 bf = *(const short8*)(wf + ((size_t)(ks * 8 + nt) * 64 + lane) * 8);
      acc[nt] = __builtin_amdgcn_mfma_f32_16x16x32_bf16(af, bf, acc[nt], 0, 0, 0);
    }
  }

  const int odd = c & 1;
#pragma unroll
  for (int r = 0; r < 4; ++r) {
    const int row = r0 + g * 4 + r;
    if (row >= n) continue;
    unsigned int* dp = Wxb + (size_t)row * 64;
#pragma unroll
    for (int ntp = 0; ntp < 4; ++ntp) {
      float ve = acc[ntp][r], vo = acc[ntp + 4][r];
      float vex = __shfl_xor(ve, 1, 64);
      float vox = __shfl_xor(vo, 1, 64);
      const int nt = odd ? ntp + 4 : ntp;
      dp[nt * 8 + (c >> 1)] = cvt_pk_bf16(odd ? vox : ve, odd ? vo : vex);
    }
  }

  float aiv[8], ajv[8];
#pragma unroll
  for (int nt = 0; nt < 8; ++nt) {
    const int hh = nt >> 1, ch = (nt & 1) * 16 + c;
    aiv[nt] = attn[hh * 64 + ch];
    ajv[nt] = attn[hh * 64 + 32 + ch];
  }
#pragma unroll
  for (int r = 0; r < 4; ++r) {
    float pih[4], pjh[4];
#pragma unroll
    for (int h = 0; h < 4; ++h) {
      pih[h] = acc[2 * h][r] * aiv[2 * h] + acc[2 * h + 1][r] * aiv[2 * h + 1];
      pjh[h] = acc[2 * h][r] * ajv[2 * h] + acc[2 * h + 1][r] * ajv[2 * h + 1];
    }
#pragma unroll
    for (int m = 1; m < 16; m <<= 1) {
#pragma unroll
      for (int h = 0; h < 4; ++h) {
        pih[h] += __shfl_xor(pih[h], m, 64);
        pjh[h] += __shfl_xor(pjh[h], m, 64);
      }
    }
    const int row = r0 + g * 4 + r;
    if (c == 0 && row < n) {
#pragma unroll
      for (int h = 0; h < 4; ++h) {
        s_i[(size_t)row * 4 + h] = pih[h];
        s_j[(size_t)row * 4 + h] = pjh[h];
      }
    }
  }
}

// ---------------------------------------------------------------- bin1
__global__ void k_bin1(const int* __restrict__ edges, const int* __restrict__ gcnt,
                       int* __restrict__ gcur, unsigned int* __restrict__ tmp, int E) {
  __shared__ int ws[4];
  __shared__ int bst_s[256];
  __shared__ int lcnt[256];
  __shared__ int lbase[256];
  const int t = threadIdx.x;
  const int excl = blk_excl_scan(gcnt[t], ws);
  bst_s[t] = excl;
  lcnt[t] = 0;
  __syncthreads();
  const int base = blockIdx.x * (256 * BIN_VPT);
  unsigned int pv[BIN_VPT];
  int rk[BIN_VPT];
#pragma unroll
  for (int j = 0; j < BIN_VPT; ++j) {
    int e = base + j * 256 + t;
    if (e < E) {
      unsigned int s = (unsigned int)edges[e];
      unsigned int d = (unsigned int)edges[E + e];
      pv[j] = s | (d << 16);
      rk[j] = atomicAdd(&lcnt[d >> 8], 1);
    } else {
      pv[j] = 0u;
      rk[j] = -1;
    }
  }
  __syncthreads();
  const int c = lcnt[t];
  lbase[t] = bst_s[t] + (c ? atomicAdd(&gcur[t], c) : 0);
  __syncthreads();
#pragma unroll
  for (int j = 0; j < BIN_VPT; ++j) {
    if (rk[j] >= 0) {
      const int b = pv[j] >> 24;  // dst >> 8
      tmp[lbase[b] + rk[j]] = pv[j];
    }
  }
}

// ---------------------------------------------------------------- bin2
__global__ void k_bin2(const unsigned int* __restrict__ tmp, const int* __restrict__ gcnt,
                       int* __restrict__ csr, int* __restrict__ offs,
                       int* __restrict__ cnts, int n) {
  __shared__ int ws[4];
  __shared__ int bst_s[256];
  __shared__ int nc[256];
  const int b = blockIdx.x;
  const int t = threadIdx.x;
  bst_s[t] = blk_excl_scan(gcnt[t], ws);
  nc[t] = 0;
  __syncthreads();
  const int base = bst_s[b], cnt = gcnt[b];
  for (int i = t; i < cnt; i += 256)
    atomicAdd(&nc[(tmp[base + i] >> 16) & 255], 1);
  __syncthreads();
  const int node = b * 256 + t;
  const int c = nc[t];
  if (node < n) cnts[node] = c;
  __syncthreads();           // blk_excl_scan reuses ws; ensure count phase done
  const int excl = blk_excl_scan(c, ws);
  if (node < n) offs[node] = base + excl;
  __syncthreads();           // everyone done reading nc from count phase
  nc[t] = excl;              // becomes local cursor
  __syncthreads();
  for (int i = t; i < cnt; i += 256) {
    unsigned int v = tmp[base + i];
    int pos = atomicAdd(&nc[(v >> 16) & 255], 1);
    csr[base + pos] = (int)(v & 0xFFFFu);
  }
}

// ---------------------------------------------------------------- agg + GEMM2
// 4 waves/block (256 thr), 16 nodes/block, 4 consecutive nodes per wave.
#define AGG_EDGE(e)                                                     \
  {                                                                     \
    int s_ = lsrc[wv][e];                                               \
    float p_ = lp[wv][e][h];                                            \
    unsigned int w_ = Wxb[(unsigned)(s_ << 6) | (unsigned)lane];        \
    acc.x += p_ * bflo(w_);                                             \
    acc.y += p_ * bfhi(w_);                                             \
    smh += p_;                                                          \
  }

__global__ void k_aggm(const unsigned int* __restrict__ Wxb, const float* __restrict__ s_i,
                       const float* __restrict__ s_j, const int* __restrict__ offs,
                       const int* __restrict__ cnts, const int* __restrict__ csr_src,
                       const unsigned short* __restrict__ owf, const float* __restrict__ ob,
                       float* __restrict__ out, int n) {
  __shared__ unsigned int aTile[16][65];
  __shared__ int   lsrc[4][64];
  __shared__ float lp[4][64][4];
  const int lane = threadIdx.x & 63;
  const int wv = threadIdx.x >> 6;
  const int nd0 = blockIdx.x * 16;
  const int nd0w = nd0 + wv * 4;       // first of this wave's 4 nodes
  const int h = lane >> 4;

  // per-node degrees in lanes 0..3; boundaries b0<b1<b2 within the wave span
  int degv = 0;
  if (lane < 4 && nd0w + lane < n) degv = cnts[nd0w + lane];
  const int wbase = (nd0w < n) ? offs[nd0w] : 0;
  const int d0 = __shfl(degv, 0, 64), d1 = __shfl(degv, 1, 64);
  const int d2 = __shfl(degv, 2, 64), d3 = __shfl(degv, 3, 64);
  const int b0 = d0, b1 = d0 + d1, b2 = b1 + d2;
  const int tot = b2 + d3;

  int cur = 0;
  int rem = d0;
  float2 acc = make_float2(0.f, 0.f);
  float smh = 0.f;

  // leading zero-degree nodes
  while (cur < 4 && rem == 0) {
    if (nd0w + cur < n) aTile[(wv << 2) + cur][lane] = 0u;  // agg row = 0
    ++cur;
    rem = (cur == 1) ? d1 : (cur == 2) ? d2 : (cur == 3) ? d3 : 0;
  }

  for (int c0 = 0; c0 < tot; c0 += 64) {
    const int m = min(64, tot - c0);
    if (lane < m) {
      const int pos = c0 + lane;
      const int src = csr_src[wbase + pos];
      const int nl = (pos >= b0) + (pos >= b1) + (pos >= b2);
      const float4 sj = *(const float4*)(s_j + (size_t)(nd0w + nl) * 4);
      const float4 si = *(const float4*)(s_i + (size_t)src * 4);
      float4 p;
      p.x = __expf(lrelu(si.x + sj.x));
      p.y = __expf(lrelu(si.y + sj.y));
      p.z = __expf(lrelu(si.z + sj.z));
      p.w = __expf(lrelu(si.w + sj.w));
      lsrc[wv][lane] = src;
      *(float4*)&lp[wv][lane][0] = p;
    }
    asm volatile("s_waitcnt lgkmcnt(0)" ::: "memory");  // same-wave LDS RAW
    int k = 0;
    while (k < m) {
      const int take = min(m - k, rem);
      int e = k;
      const int end = k + take;
      for (; e + 8 <= end; e += 8) {  // 8 independent 256B row loads in flight
        AGG_EDGE(e + 0) AGG_EDGE(e + 1) AGG_EDGE(e + 2) AGG_EDGE(e + 3)
        AGG_EDGE(e + 4) AGG_EDGE(e + 5) AGG_EDGE(e + 6) AGG_EDGE(e + 7)
      }
      for (; e + 4 <= end; e += 4) {
        AGG_EDGE(e + 0) AGG_EDGE(e + 1) AGG_EDGE(e + 2) AGG_EDGE(e + 3)
      }
      for (; e < end; ++e) AGG_EDGE(e)
      k += take;
      rem -= take;
      while (rem == 0 && cur < 4) {  // finalize node(s); skip zero-deg
        const float inv = 1.f / (smh + 1e-16f);
        if (nd0w + cur < n)
          aTile[(wv << 2) + cur][lane] = cvt_pk_bf16(acc.x * inv, acc.y * inv);
        ++cur;
        acc.x = 0.f; acc.y = 0.f; smh = 0.f;
        rem = (cur == 1) ? d1 : (cur == 2) ? d2 : (cur == 3) ? d3 : 0;
      }
      if (cur >= 4) break;
    }
  }
  __syncthreads();

  // ---- phase 2: out-GEMM on the 16-row tile; each wave does 2 col-tiles
  const int g = lane >> 4, c = lane & 15;
#pragma unroll
  for (int t2 = 0; t2 < 2; ++t2) {
    const int nt = wv + t2 * 4;
    f32x4 o = (f32x4){0.f, 0.f, 0.f, 0.f};
#pragma unroll
    for (int ks = 0; ks < 4; ++ks) {
      uint4 au = *(const uint4*)&aTile[c][ks * 16 + g * 4];  // A row = lane&15
      short8 af = __builtin_bit_cast(short8, au);
      short8 bf = *(const short8*)(owf + ((size_t)(ks * 8 + nt) * 64 + lane) * 8);
      o = __builtin_amdgcn_mfma_f32_16x16x32_bf16(af, bf, o, 0, 0, 0);
    }
#pragma unroll
    for (int r = 0; r < 4; ++r) {
      const int row = nd0 + g * 4 + r;   // D row = (lane>>4)*4 + r
      if (row < n) {
        float v = o[r] + ob[nt * 16 + c];
        v = v > 0.f ? v : expm1f(v);
        out[(size_t)row * 128 + nt * 16 + c] = v;
      }
    }
  }
}

// ---------------------------------------------------------------- launch
extern "C" void kernel_launch(void* const* d_in, const int* in_sizes, int n_in,
                              void* d_out, int out_size, void* d_ws, size_t ws_size,
                              hipStream_t stream) {
  const float* x    = (const float*)d_in[0];
  const int*   edges = (const int*)d_in[1];   // [2,E] (src row then dst row)
  const float* W    = (const float*)d_in[2];
  const float* attn = (const float*)d_in[3];
  const float* ow   = (const float*)d_in[4];
  const float* ob   = (const float*)d_in[5];
  const int n = in_sizes[0] / 128;            // 50000 (< 65536: u32 edge pack)
  const int E = in_sizes[1] / 2;
  float* out = (float*)d_out;

  char* wp = (char*)d_ws;
  auto alloc = [&](size_t bytes) {
    char* p = wp;
    wp += (bytes + 255) & ~(size_t)255;
    return p;
  };
  unsigned short* wf  = (unsigned short*)alloc(2048 * 8 * 2);
  unsigned short* owf = (unsigned short*)alloc(2048 * 8 * 2);
  unsigned int*   Wxb = (unsigned int*)alloc((size_t)n * 64 * 4);
  float* s_i    = (float*)alloc((size_t)n * 4 * 4);
  float* s_j    = (float*)alloc((size_t)n * 4 * 4);
  int*   gcnt   = (int*)alloc(256 * 4);
  int*   gcur   = (int*)alloc(256 * 4);
  int*   offs   = (int*)alloc((size_t)n * 4);
  int*   cnts   = (int*)alloc((size_t)n * 4);
  unsigned int* tmp = (unsigned int*)alloc((size_t)E * 4);
  int*   csr    = (int*)alloc((size_t)E * 4);

  dim3 blk(256);
  const int NB = (n + 255) / 256;                            // node buckets (196)
  const int EB = (E + 256 * BIN_VPT - 1) / (256 * BIN_VPT);  // edge blocks (196)
  const int strips = (n + 15) / 16;
  const int gemmBlocks = (strips + 3) / 4;

  k_setup<<<16, blk, 0, stream>>>(W, ow, wf, owf, gcnt, gcur);
  k_gemm1b<<<gemmBlocks + EB, blk, 0, stream>>>(x, wf, attn, Wxb, s_i, s_j, n,
                                                edges + E, gcnt, E, gemmBlocks);
  k_bin1<<<EB, blk, 0, stream>>>(edges, gcnt, gcur, tmp, E);
  k_bin2<<<NB, blk, 0, stream>>>(tmp, gcnt, csr, offs, cnts, n);
  k_aggm<<<(n + 15) / 16, blk, 0, stream>>>(Wxb, s_i, s_j, offs, cnts, csr,
                                            owf, ob, out, n);
}